// Round 12
// baseline (226.659 us; speedup 1.0000x reference)
//
#include <hip/hip_runtime.h>

// DiscoDownBlock: GN1 -> 1x1 MLP (expand/gelu/project) + residual -> DISCO S2 conv
//                 -> GN2 -> gelu.  Outputs: skip [2,128,181,360], x_down [2,256,91,180]
//
// Round 12 (on R11 base):
//  - k_mlp launch_bounds(256,5): 5 blocks/CU (LDS 32KB allows), no structural change.
//  - k_prep merges gn1_partial + wcvt + wcvt_w2 (2 fewer serialized launches).
//  - k_dgemm 1024 blocks (64-row n-tiles, wave 32n x 64co): 4 blocks/CU for the
//    latency-bound no-LDS GEMM; coh-pairs share Yt panels in-XCD.

#define HW      65160      // 181*360
#define HIN     181
#define WIN     360
#define HOUT    91
#define WOUT    180
#define CIN     128
#define COUT    256
#define KB      7
#define NNZ     16
#define N_GN1   1042560    // 16*HW
#define N_GN2   524160     // 32*91*180
#define NPB     16380      // 91*180 (per-batch n)

typedef float  f32x4  __attribute__((ext_vector_type(4)));
typedef __bf16 bf16x8 __attribute__((ext_vector_type(8)));

__device__ __forceinline__ unsigned short f2b(float v){
    return __builtin_bit_cast(unsigned short, (__bf16)v);
}
__device__ __forceinline__ unsigned pkbf(float a, float b){
    return (unsigned)__builtin_bit_cast(unsigned short, (__bf16)a)
         | ((unsigned)__builtin_bit_cast(unsigned short, (__bf16)b) << 16);
}
__device__ __forceinline__ float blo(unsigned u){ return __uint_as_float(u << 16); }
__device__ __forceinline__ float bhi(unsigned u){ return __uint_as_float(u & 0xffff0000u); }

// gelu via sigmoid identity: 0.5v(1+tanh z) = v * sigma(2z).
__device__ __forceinline__ float gelu_f(float v){
    float z = v * __builtin_fmaf(0.0356774081363f, v*v, 0.7978845608028654f);
    float e = __builtin_amdgcn_exp2f(-2.8853900817779268f * z);
    return v * __builtin_amdgcn_rcpf(1.0f + e);
}

// ---------------- prep: GN1 partials + weight converts (merged) ----------------
// grid 2432 x 256: [0,2048) gn1_partial, [2048,2304) wcvt, [2304,2432) wcvt_w2.
__global__ __launch_bounds__(256) void k_prep(
    const float* __restrict__ x, float* __restrict__ part,
    const float* __restrict__ wsrc, unsigned short* __restrict__ wbf,
    const float* __restrict__ w2, unsigned short* __restrict__ w2b)
{
    const int blk_id = blockIdx.x;
    const int t = threadIdx.x;

    if (blk_id < 2048){
        const int bg = blk_id >> 7, blk = blk_id & 127;
        const float4* p4 = (const float4*)(x + (size_t)bg * N_GN1);
        float s = 0.f, ss = 0.f;
        for (int v = blk*256 + t; v < N_GN1/4; v += 128*256){
            float4 q = p4[v];
            s  += q.x + q.y + q.z + q.w;
            ss += q.x*q.x + q.y*q.y + q.z*q.z + q.w*q.w;
        }
        #pragma unroll
        for (int off = 32; off; off >>= 1){ s += __shfl_down(s, off); ss += __shfl_down(ss, off); }
        __shared__ float ls[4][2];
        if ((t & 63) == 0){ ls[t>>6][0] = s; ls[t>>6][1] = ss; }
        __syncthreads();
        if (t == 0){
            s  = ls[0][0] + ls[1][0] + ls[2][0] + ls[3][0];
            ss = ls[0][1] + ls[1][1] + ls[2][1] + ls[3][1];
            part[(bg*128 + blk)*2]     = s;
            part[(bg*128 + blk)*2 + 1] = ss;
        }
    } else if (blk_id < 2304){
        const int co = blk_id - 2048;
        for (int r = t; r < 896; r += 256){
            int k = r >> 7, c = r & 127;
            wbf[co*896 + r] = f2b(wsrc[co*896 + c*7 + k]);
        }
    } else {
        const int i = (blk_id - 2304)*256 + t;
        if (i < 32768) w2b[i] = f2b(w2[i]);
    }
}

__global__ __launch_bounds__(128) void k_gn1_final(const float* __restrict__ part,
                                                   float* __restrict__ stat){
    const int bg = blockIdx.x, t = threadIdx.x;
    float s  = part[(bg*128 + t)*2];
    float ss = part[(bg*128 + t)*2 + 1];
    #pragma unroll
    for (int off = 32; off; off >>= 1){ s += __shfl_down(s, off); ss += __shfl_down(ss, off); }
    __shared__ float ls[2][2];
    if ((t & 63) == 0){ ls[t>>6][0] = s; ls[t>>6][1] = ss; }
    __syncthreads();
    if (t == 0){
        s  = ls[0][0] + ls[1][0];
        ss = ls[0][1] + ls[1][1];
        float m = s / (float)N_GN1;
        float v = ss / (float)N_GN1 - m*m;
        stat[bg*2]     = m;
        stat[bg*2 + 1] = 1.0f / sqrtf(v + 1e-5f);
    }
}

// GN1 fold: w1f[b][oc][c] = bf16(w1[oc][c] * a[b][c]); b1f[b][oc] = b1[oc] + sum_c w1*bb
__global__ __launch_bounds__(64) void k_wfold(
    const float* __restrict__ w1, const float* __restrict__ b1,
    const float* __restrict__ stat, const float* __restrict__ g1,
    const float* __restrict__ be1,
    unsigned short* __restrict__ w1f, float* __restrict__ b1f)
{
    const int id = blockIdx.x;         // b*256 + oc
    const int b = id >> 8, oc = id & 255;
    const int l = threadIdx.x;
    float acc = 0.f;
    #pragma unroll
    for (int j = 0; j < 2; ++j){
        const int c = l + j*64;
        float m = stat[(b*8 + (c >> 4))*2];
        float r = stat[(b*8 + (c >> 4))*2 + 1];
        float a = r * g1[c];
        float bb = be1[c] - m*a;
        float wv = w1[oc*128 + c];
        w1f[((size_t)b*256 + oc)*128 + c] = f2b(wv * a);
        acc += wv * bb;
    }
    #pragma unroll
    for (int off = 32; off; off >>= 1) acc += __shfl_down(acc, off);
    if (l == 0) b1f[b*256 + oc] = b1[oc] + acc;
}

// ---------------- fused MLP + residual (MFMA, 2-half pipeline) ----------------
// grid (1019, 2), 256 thr (4 waves). 64-pixel tile.
// LDS: xns [64p][128c] raw-x bf16 16KB + h1h [64p][128 ocl] 16KB = 32KB -> 5 blocks/CU.
__global__ __launch_bounds__(256, 5) void k_mlp(
    const float* __restrict__ x,
    const unsigned short* __restrict__ w1f, const float* __restrict__ b1f,
    const unsigned short* __restrict__ w2b, const float* __restrict__ b2,
    float* __restrict__ skip, unsigned short* __restrict__ sbf)
{
    __shared__ unsigned short xns[64*128];   // rows 256B, swizzled; raw x bf16
    __shared__ unsigned short h1h[64*128];   // rows 256B, swizzled (one oc-half)

    const int t = threadIdx.x;
    const int b = blockIdx.y;
    const int pix0 = blockIdx.x * 64;
    const int valid = min(64, HW - pix0);

    const int w  = t >> 6, l = t & 63;
    const int lr = l & 15, lk = l >> 4;

    { // stage raw x as bf16 (GN1 is folded into w1f/b1f)
        const int p = l;
        const unsigned sw = ((unsigned)(p & 7)) << 4;
        const float* xb = x + (size_t)b*128*HW + pix0 + p;
        #pragma unroll
        for (int i = 0; i < 8; ++i){
            const int c0 = w*32 + i*4;
            uint2 pk;
            if (p < valid){
                pk.x = pkbf(xb[(size_t)(c0+0)*HW], xb[(size_t)(c0+1)*HW]);
                pk.y = pkbf(xb[(size_t)(c0+2)*HW], xb[(size_t)(c0+3)*HW]);
            } else { pk.x = 0u; pk.y = 0u; }
            *(uint2*)((char*)xns + p*256 + (((unsigned)(c0*2)) ^ sw)) = pk;
        }
    }
    __syncthreads();

    // GEMM2 accumulator C[p][c]: pm 0..3 (p 16-blocks), cn 0..1 (c 16-blocks)
    f32x4 acc2[4][2];
    {
        const float bv0 = b2[w*32 + lr];
        const float bv1 = b2[w*32 + 16 + lr];
        #pragma unroll
        for (int pm = 0; pm < 4; ++pm){
            acc2[pm][0] = (f32x4)bv0;
            acc2[pm][1] = (f32x4)bv1;
        }
    }

    const unsigned short* w1p = w1f + (size_t)b*256*128;

    #pragma unroll
    for (int half = 0; half < 2; ++half){
        // ---- GEMM1 (this half): h1[ocl = w*32..+32][p], oc = half*128 + ocl ----
        {
            f32x4 acc1[2][4];
            #pragma unroll
            for (int m = 0; m < 2; ++m){
                float4 bv = *(const float4*)(b1f + b*256 + half*128 + w*32 + m*16 + lk*4);
                #pragma unroll
                for (int nf = 0; nf < 4; ++nf) acc1[m][nf] = __builtin_bit_cast(f32x4, bv);
            }
            const unsigned short* wr = w1p + (size_t)(half*128 + w*32 + lr)*128 + lk*8;
            #pragma unroll
            for (int ks = 0; ks < 4; ++ks){
                bf16x8 af[2];
                #pragma unroll
                for (int m = 0; m < 2; ++m)
                    af[m] = __builtin_bit_cast(bf16x8, *(const uint4*)(wr + m*16*128 + ks*32));
                bf16x8 bfv[4];
                #pragma unroll
                for (int nf = 0; nf < 4; ++nf){
                    const int p = nf*16 + lr;
                    unsigned off = (unsigned)(p*256)
                                 + (((unsigned)(ks*64 + lk*16)) ^ (((unsigned)(p & 7)) << 4));
                    bfv[nf] = __builtin_bit_cast(bf16x8, *(const uint4*)((const char*)xns + off));
                }
                #pragma unroll
                for (int m = 0; m < 2; ++m)
                    #pragma unroll
                    for (int nf = 0; nf < 4; ++nf)
                        acc1[m][nf] = __builtin_amdgcn_mfma_f32_16x16x32_bf16(af[m], bfv[nf], acc1[m][nf], 0, 0, 0);
            }
            // gelu + pack to h1h (local oc index)
            #pragma unroll
            for (int m = 0; m < 2; ++m){
                const int oc0 = w*32 + m*16 + lk*4;
                #pragma unroll
                for (int nf = 0; nf < 4; ++nf){
                    const int p = nf*16 + lr;
                    uint2 pk;
                    pk.x = pkbf(gelu_f(acc1[m][nf][0]), gelu_f(acc1[m][nf][1]));
                    pk.y = pkbf(gelu_f(acc1[m][nf][2]), gelu_f(acc1[m][nf][3]));
                    unsigned off = (unsigned)(p*256)
                                 + (((unsigned)(oc0*2)) ^ (((unsigned)(p & 7)) << 4));
                    *(uint2*)((char*)h1h + off) = pk;
                }
            }
        }
        __syncthreads();

        // ---- GEMM2 partial: accumulate K = this half's 128 oc ----
        {
            const unsigned short* wr = w2b + (size_t)(w*32 + lr)*256 + half*128 + lk*8;
            #pragma unroll
            for (int ks = 0; ks < 4; ++ks){
                bf16x8 bfw[2];
                #pragma unroll
                for (int cn = 0; cn < 2; ++cn)
                    bfw[cn] = __builtin_bit_cast(bf16x8, *(const uint4*)(wr + cn*16*256 + ks*32));
                bf16x8 afh[4];
                #pragma unroll
                for (int pm = 0; pm < 4; ++pm){
                    const int p = pm*16 + lr;
                    unsigned off = (unsigned)(p*256)
                                 + (((unsigned)(ks*64 + lk*16)) ^ (((unsigned)(p & 7)) << 4));
                    afh[pm] = __builtin_bit_cast(bf16x8, *(const uint4*)((const char*)h1h + off));
                }
                #pragma unroll
                for (int pm = 0; pm < 4; ++pm)
                    #pragma unroll
                    for (int cn = 0; cn < 2; ++cn)
                        acc2[pm][cn] = __builtin_amdgcn_mfma_f32_16x16x32_bf16(afh[pm], bfw[cn], acc2[pm][cn], 0, 0, 0);
            }
        }
        if (half == 0) __syncthreads();      // before G1b overwrites h1h
    }

    // ---- epilogue: residual from xns (raw-x bf16, still live); float4 skip
    //      stores; scalar u16 sbf stores ----
    #pragma unroll
    for (int pm = 0; pm < 4; ++pm){
        const int p0 = pm*16 + lk*4;
        if (p0 < valid){                     // valid is a multiple of 4 (tail = 8)
            #pragma unroll
            for (int cn = 0; cn < 2; ++cn){
                const int c = w*32 + cn*16 + lr;
                size_t base = (size_t)(b*128 + c)*HW + pix0 + p0;
                float4 o;
                #pragma unroll
                for (int r = 0; r < 4; ++r){
                    const int p = p0 + r;
                    unsigned off = (unsigned)(p*256)
                                 + (((unsigned)(c*2)) ^ (((unsigned)(p & 7)) << 4));
                    unsigned short us = *(const unsigned short*)((const char*)xns + off);
                    ((float*)&o)[r] = acc2[pm][cn][r] + blo((unsigned)us);
                }
                *(float4*)(skip + base) = o;
                if (sbf){
                    unsigned short* sp = sbf + ((size_t)b*HW + pix0 + p0)*128 + c;
                    sp[0]   = f2b(o.x);
                    sp[128] = f2b(o.y);
                    sp[256] = f2b(o.z);
                    sp[384] = f2b(o.w);
                }
            }
        }
    }
}

// ---------------- Y build: gather + psi reduce -> Y_t[n][ck] bf16 ----------------
// grid (6 wo-tiles of 32, 91 ho, 2 b), 256 thr = 32 wol x 8 cq.
__global__ __launch_bounds__(256) void k_ybuild(
    const unsigned short* __restrict__ sbf,
    const float* __restrict__ psi_v, const int* __restrict__ psi_hi, const int* __restrict__ psi_wi,
    unsigned short* __restrict__ Yt)
{
    __shared__ int   offh[16];
    __shared__ int   wis[16];
    __shared__ float psis[112];

    const int t   = threadIdx.x;
    const int wot = blockIdx.x, ho = blockIdx.y, b = blockIdx.z;

    if (t < 112) psis[t] = psi_v[((t >> 4)*HOUT + ho)*NNZ + (t & 15)];
    if (t < 16){ offh[t] = psi_hi[ho*NNZ + t] * WIN; wis[t] = psi_wi[ho*NNZ + t]; }
    __syncthreads();

    const int wol = t >> 3, cq = t & 7;
    const int wo  = wot*32 + wol;
    const bool valid = (wo < WOUT);
    const int wo_c = valid ? wo : (WOUT - 1);

    int offs[16];
    #pragma unroll
    for (int n = 0; n < 16; ++n){
        int wv = wis[n] + 2*wo_c;
        wv = (wv >= WIN) ? (wv - WIN) : wv;
        offs[n] = offh[n] + wv;
    }

    const unsigned short* sb = sbf + (size_t)b * HW * 128;
    unsigned short* yrow = Yt + (size_t)(b*NPB + ho*WOUT + wo_c) * 896;

    #pragma unroll 1
    for (int cc = 0; cc < 4; ++cc){
        const int c0 = cc*32 + cq*4;
        float ya[4][7];
        #pragma unroll
        for (int ci = 0; ci < 4; ++ci)
            #pragma unroll
            for (int k = 0; k < 7; ++k) ya[ci][k] = 0.f;

        #pragma unroll 2
        for (int n = 0; n < 16; ++n){
            uint2 q = *(const uint2*)(sb + (size_t)offs[n]*128 + c0);
            float g0 = blo(q.x), g1 = bhi(q.x), g2 = blo(q.y), g3 = bhi(q.y);
            #pragma unroll
            for (int k = 0; k < 7; ++k){
                float pv = psis[k*16 + n];
                ya[0][k] += pv*g0; ya[1][k] += pv*g1;
                ya[2][k] += pv*g2; ya[3][k] += pv*g3;
            }
        }
        if (valid){
            #pragma unroll
            for (int k = 0; k < 7; ++k){
                uint2 pk;
                pk.x = pkbf(ya[0][k], ya[1][k]);
                pk.y = pkbf(ya[2][k], ya[3][k]);
                *(uint2*)(yrow + k*128 + c0) = pk;
            }
        }
    }
}

// ---------------- DISCO GEMM: D[n][co] = Y_t @ W^T, no LDS ----------------
// grid 1024 blocks (XCD-swizzled), 256 thr (4 waves, 32n x 64co each).
__global__ __launch_bounds__(256) void k_dgemm(
    const unsigned short* __restrict__ Yt, const unsigned short* __restrict__ wbf,
    const float* __restrict__ bias,
    unsigned short* __restrict__ xdb, float* __restrict__ part)
{
    const int flat = blockIdx.x + 256*(blockIdx.y + 2*blockIdx.z);
    const int rem  = (flat & 7)*128 + (flat >> 3);     // XCD-contiguous (1024 = 8*128)
    const int coh  = rem & 1;
    const int nt   = (rem >> 1) & 255;                 // 64-row n tile
    const int b    = rem >> 9;

    const int t = threadIdx.x;
    const int w = t >> 6, l = t & 63;
    const int lr = l & 15, lk = l >> 4;
    const int wn2 = w >> 1, wc = w & 1;

    const int n0  = nt*64 + wn2*32;
    const int co0 = coh*128 + wc*64;

    const unsigned short* pa[2];
    const unsigned short* pb[4];
    #pragma unroll
    for (int i = 0; i < 2; ++i)
        pa[i] = Yt + (size_t)(b*NPB + n0 + i*16 + lr)*896 + lk*8;
    #pragma unroll
    for (int j = 0; j < 4; ++j)
        pb[j] = wbf + (size_t)(co0 + j*16 + lr)*896 + lk*8;

    f32x4 acc[2][4];
    #pragma unroll
    for (int i = 0; i < 2; ++i)
        #pragma unroll
        for (int j = 0; j < 4; ++j) acc[i][j] = (f32x4)0.f;

    #pragma unroll 2
    for (int ks = 0; ks < 28; ++ks){
        bf16x8 af[2], bf[4];
        #pragma unroll
        for (int i = 0; i < 2; ++i)
            af[i] = __builtin_bit_cast(bf16x8, *(const uint4*)(pa[i] + ks*32));
        #pragma unroll
        for (int j = 0; j < 4; ++j)
            bf[j] = __builtin_bit_cast(bf16x8, *(const uint4*)(pb[j] + ks*32));
        #pragma unroll
        for (int i = 0; i < 2; ++i)
            #pragma unroll
            for (int j = 0; j < 4; ++j)
                acc[i][j] = __builtin_amdgcn_mfma_f32_16x16x32_bf16(af[i], bf[j], acc[i][j], 0, 0, 0);
    }

    float s[2] = {0.f, 0.f}, ss[2] = {0.f, 0.f};
    #pragma unroll
    for (int j = 0; j < 4; ++j){
        const int co = co0 + j*16 + lr;
        const float bv = bias[co];
        unsigned short* outp = xdb + (size_t)(b*256 + co)*NPB;
        const int jp = j >> 1;
        #pragma unroll
        for (int i = 0; i < 2; ++i){
            const int nb = n0 + i*16 + lk*4;
            if (nb < NPB){
                float o0 = acc[i][j][0] + bv, o1 = acc[i][j][1] + bv;
                float o2 = acc[i][j][2] + bv, o3 = acc[i][j][3] + bv;
                uint2 pk; pk.x = pkbf(o0, o1); pk.y = pkbf(o2, o3);
                *(uint2*)(outp + nb) = pk;
                s[jp]  += o0 + o1 + o2 + o3;
                ss[jp] += o0*o0 + o1*o1 + o2*o2 + o3*o3;
            }
        }
    }
    #pragma unroll
    for (int off = 32; off; off >>= 1){
        s[0] += __shfl_down(s[0], off); ss[0] += __shfl_down(ss[0], off);
        s[1] += __shfl_down(s[1], off); ss[1] += __shfl_down(ss[1], off);
    }
    if (l == 0){
        const int bid = (b*2 + coh)*256 + nt;
        part[(bid*8 + w*2 + 0)*2]     = s[0];
        part[(bid*8 + w*2 + 0)*2 + 1] = ss[0];
        part[(bid*8 + w*2 + 1)*2]     = s[1];
        part[(bid*8 + w*2 + 1)*2 + 1] = ss[1];
    }
}

// ---------------- GN2 finalize (split path) ----------------
// g = coh*4 + wc*2 + jp; sum over nt 0..255, wn2 0..1.
__global__ __launch_bounds__(256) void k_gn2_final_s(const float* __restrict__ part,
                                                     float* __restrict__ stat){
    const int bg = blockIdx.x, b = bg >> 3, g = bg & 7, t = threadIdx.x;
    const int coh = g >> 2, wc = (g >> 1) & 1, jp = g & 1;
    float s = 0.f, ss = 0.f;
    for (int i = t; i < 512; i += 256){
        const int nt = i >> 1, wn2 = i & 1;
        const int bid = (b*2 + coh)*256 + nt;
        const int slot = (wn2*2 + wc)*2 + jp;
        s  += part[(bid*8 + slot)*2];
        ss += part[(bid*8 + slot)*2 + 1];
    }
    #pragma unroll
    for (int off = 32; off; off >>= 1){ s += __shfl_down(s, off); ss += __shfl_down(ss, off); }
    __shared__ float ls[4][2];
    if ((t & 63) == 0){ ls[t>>6][0] = s; ls[t>>6][1] = ss; }
    __syncthreads();
    if (t == 0){
        s  = ls[0][0] + ls[1][0] + ls[2][0] + ls[3][0];
        ss = ls[0][1] + ls[1][1] + ls[2][1] + ls[3][1];
        float m = s / (float)N_GN2;
        float v = ss / (float)N_GN2 - m*m;
        stat[bg*2]     = m;
        stat[bg*2 + 1] = 1.0f / sqrtf(v + 1e-5f);
    }
}

// ---------------- GN2 apply + gelu: bf16 in -> fp32 out (split path) ----------------
__global__ __launch_bounds__(256) void k_gn2_apply_s(const unsigned short* __restrict__ xdb,
                                                     float* __restrict__ outd,
                                                     const float* __restrict__ stat,
                                                     const float* __restrict__ g2a,
                                                     const float* __restrict__ be2){
    const int gid = blockIdx.x*256 + threadIdx.x;
    const int stride = gridDim.x*256;
    for (int v = gid; v < 2096640; v += stride){
        uint2 q = ((const uint2*)xdb)[v];
        int i  = v << 2;
        int bc = i / 16380;
        int co = bc & 255, b = bc >> 8;
        float m  = stat[(b*8 + (co >> 5))*2];
        float r  = stat[(b*8 + (co >> 5))*2 + 1];
        float a  = r * g2a[co];
        float bb = be2[co] - m*a;
        float4 o;
        o.x = gelu_f(__builtin_fmaf(blo(q.x), a, bb));
        o.y = gelu_f(__builtin_fmaf(bhi(q.x), a, bb));
        o.z = gelu_f(__builtin_fmaf(blo(q.y), a, bb));
        o.w = gelu_f(__builtin_fmaf(bhi(q.y), a, bb));
        ((float4*)outd)[v] = o;
    }
}

// ================= FALLBACK (fused disco, fp32 in-place apply) =================
__global__ __launch_bounds__(256, 2) void k_disco_fb(
    const float* __restrict__ skip,
    const float* __restrict__ psi_v, const int* __restrict__ psi_hi, const int* __restrict__ psi_wi,
    const unsigned short* __restrict__ wbf, const float* __restrict__ bias,
    float* __restrict__ xdown, float* __restrict__ part)
{
    __shared__ unsigned short yT[96*256];

    const int t   = threadIdx.x;
    const int woh = blockIdx.x;
    const int ho  = blockIdx.y;
    const int z   = blockIdx.z;
    const int b   = z >> 1, coh = z & 1;
    const int co0 = coh * 128;
    const int wo0 = woh * 90;

    const int w  = t >> 6;
    const int l  = t & 63;
    const int wm = w >> 1, wn = w & 1;

    const int wol = t & 31;
    const int cq  = t >> 5;
    const unsigned sw = (unsigned)(wol & 7) << 4;

    const float* skipb = skip + (size_t)b * (128*HW);

    f32x4 acc[4][3];
    #pragma unroll
    for (int m = 0; m < 4; ++m)
        #pragma unroll
        for (int nf = 0; nf < 3; ++nf) acc[m][nf] = (f32x4)0.f;

    #pragma unroll 1
    for (int cc = 0; cc < 4; ++cc){
        __syncthreads();
        const float* bp0 = skipb + (size_t)(cc*32 + cq*4 + 0)*HW;
        const float* bp1 = skipb + (size_t)(cc*32 + cq*4 + 1)*HW;
        const float* bp2 = skipb + (size_t)(cc*32 + cq*4 + 2)*HW;
        const float* bp3 = skipb + (size_t)(cc*32 + cq*4 + 3)*HW;

        float ya[3][4][7];
        #pragma unroll
        for (int wj = 0; wj < 3; ++wj)
            #pragma unroll
            for (int ci = 0; ci < 4; ++ci)
                #pragma unroll
                for (int k = 0; k < 7; ++k) ya[wj][ci][k] = 0.f;

        #pragma unroll 2
        for (int n = 0; n < NNZ; ++n){
            const int hi = psi_hi[ho*NNZ + n];
            const int wi = psi_wi[ho*NNZ + n];
            float ps[7];
            #pragma unroll
            for (int k = 0; k < 7; ++k) ps[k] = psi_v[(k*HOUT + ho)*NNZ + n];
            const int rowb = hi * WIN;
            #pragma unroll
            for (int wj = 0; wj < 3; ++wj){
                int wv = wi + 2*(wo0 + wol + 32*wj);
                wv = (wv >= 720) ? (wv - 720) : (wv >= 360 ? (wv - 360) : wv);
                const int off = rowb + wv;
                float g0 = bp0[off], g1 = bp1[off], g2 = bp2[off], g3 = bp3[off];
                #pragma unroll
                for (int k = 0; k < 7; ++k){
                    float pv = ps[k];
                    ya[wj][0][k] += pv*g0; ya[wj][1][k] += pv*g1;
                    ya[wj][2][k] += pv*g2; ya[wj][3][k] += pv*g3;
                }
            }
        }
        #pragma unroll
        for (int wj = 0; wj < 3; ++wj){
            char* row = (char*)yT + (wol + 32*wj)*512;
            #pragma unroll
            for (int k = 0; k < 7; ++k){
                unsigned base = ((unsigned)(k*64 + cq*8)) ^ sw;
                *(unsigned*)(row + base)     = pkbf(ya[wj][0][k], ya[wj][1][k]);
                *(unsigned*)(row + base + 4) = pkbf(ya[wj][2][k], ya[wj][3][k]);
            }
        }
        __syncthreads();

        const unsigned short* wrow = wbf + (size_t)(co0 + wm*64 + (l & 15))*896
                                         + cc*32 + ((l >> 4) << 3);
        #pragma unroll
        for (int k = 0; k < 7; ++k){
            bf16x8 af[4];
            #pragma unroll
            for (int m = 0; m < 4; ++m)
                af[m] = __builtin_bit_cast(bf16x8,
                          *(const uint4*)(wrow + (size_t)m*16*896 + k*128));
            bf16x8 bfv[3];
            #pragma unroll
            for (int nf = 0; nf < 3; ++nf){
                const int wo_l = wn*48 + nf*16 + (l & 15);
                unsigned off = (unsigned)(wo_l*512)
                             + (((unsigned)(k*64) + ((unsigned)(l >> 4) << 4))
                                ^ ((unsigned)(wo_l & 7) << 4));
                bfv[nf] = __builtin_bit_cast(bf16x8, *(const uint4*)((const char*)yT + off));
            }
            #pragma unroll
            for (int m = 0; m < 4; ++m)
                #pragma unroll
                for (int nf = 0; nf < 3; ++nf)
                    acc[m][nf] = __builtin_amdgcn_mfma_f32_16x16x32_bf16(af[m], bfv[nf], acc[m][nf], 0, 0, 0);
        }
    }

    float s[2] = {0.f, 0.f}, ss[2] = {0.f, 0.f};
    #pragma unroll
    for (int m = 0; m < 4; ++m){
        const int pair = m >> 1;
        const int cob = co0 + wm*64 + m*16 + ((l >> 4) << 2);
        float4 bv = *(const float4*)(bias + cob);
        #pragma unroll
        for (int nf = 0; nf < 3; ++nf){
            const int wo_t = wn*48 + nf*16 + (l & 15);
            if (wo_t < 90){
                #pragma unroll
                for (int r = 0; r < 4; ++r){
                    float v = acc[m][nf][r] + ((const float*)&bv)[r];
                    xdown[((size_t)(b*256 + cob + r)*HOUT + ho)*WOUT + wo0 + wo_t] = v;
                    s[pair] += v; ss[pair] += v*v;
                }
            }
        }
    }
    #pragma unroll
    for (int off = 32; off; off >>= 1){
        s[0] += __shfl_down(s[0], off); ss[0] += __shfl_down(ss[0], off);
        s[1] += __shfl_down(s[1], off); ss[1] += __shfl_down(ss[1], off);
    }
    if (l == 0){
        const int tid = (z*91 + ho)*2 + woh;
        part[(tid*8 + w*2 + 0)*2]     = s[0];
        part[(tid*8 + w*2 + 0)*2 + 1] = ss[0];
        part[(tid*8 + w*2 + 1)*2]     = s[1];
        part[(tid*8 + w*2 + 1)*2 + 1] = ss[1];
    }
}

__global__ __launch_bounds__(256) void k_gn2_final_fb(const float* __restrict__ part,
                                                      float* __restrict__ stat){
    const int bg = blockIdx.x, b = bg >> 3, g = bg & 7, t = threadIdx.x;
    const int coh = g >> 2, gl = g & 3, wm = gl >> 1, pair = gl & 1;
    float s = 0.f, ss = 0.f;
    for (int i = t; i < 364; i += 256){
        int ho = i >> 2, r = i & 3, woh = r >> 1, wn = r & 1;
        int tid = (((b*2 + coh)*91 + ho)*2 + woh);
        int slot = (wm*2 + wn)*2 + pair;
        s  += part[(tid*8 + slot)*2];
        ss += part[(tid*8 + slot)*2 + 1];
    }
    #pragma unroll
    for (int off = 32; off; off >>= 1){ s += __shfl_down(s, off); ss += __shfl_down(ss, off); }
    __shared__ float ls[4][2];
    if ((t & 63) == 0){ ls[t>>6][0] = s; ls[t>>6][1] = ss; }
    __syncthreads();
    if (t == 0){
        s  = ls[0][0] + ls[1][0] + ls[2][0] + ls[3][0];
        ss = ls[0][1] + ls[1][1] + ls[2][1] + ls[3][1];
        float m = s / (float)N_GN2;
        float v = ss / (float)N_GN2 - m*m;
        stat[bg*2]     = m;
        stat[bg*2 + 1] = 1.0f / sqrtf(v + 1e-5f);
    }
}

__global__ __launch_bounds__(256) void k_gn2_apply(float* __restrict__ xd,
                                                   const float* __restrict__ stat,
                                                   const float* __restrict__ g2a,
                                                   const float* __restrict__ be2){
    const int gid = blockIdx.x*256 + threadIdx.x;
    const int stride = gridDim.x*256;
    for (int v = gid; v < 2096640; v += stride){
        float4 q = ((float4*)xd)[v];
        int i  = v << 2;
        int bc = i / 16380;
        int co = bc & 255, b = bc >> 8;
        float m  = stat[(b*8 + (co >> 5))*2];
        float r  = stat[(b*8 + (co >> 5))*2 + 1];
        float a  = r * g2a[co];
        float bb = be2[co] - m*a;
        q.x = gelu_f(__builtin_fmaf(q.x, a, bb));
        q.y = gelu_f(__builtin_fmaf(q.y, a, bb));
        q.z = gelu_f(__builtin_fmaf(q.z, a, bb));
        q.w = gelu_f(__builtin_fmaf(q.w, a, bb));
        ((float4*)xd)[v] = q;
    }
}

extern "C" void kernel_launch(void* const* d_in, const int* in_sizes, int n_in,
                              void* d_out, int out_size, void* d_ws, size_t ws_size,
                              hipStream_t stream){
    const float* x      = (const float*)d_in[0];
    const float* psi_v  = (const float*)d_in[1];
    const int*   psi_hi = (const int*)d_in[2];
    const int*   psi_wi = (const int*)d_in[3];
    const float* weight = (const float*)d_in[4];
    const float* bias   = (const float*)d_in[5];
    const float* g1     = (const float*)d_in[6];
    const float* be1    = (const float*)d_in[7];
    const float* w1     = (const float*)d_in[8];
    const float* b1     = (const float*)d_in[9];
    const float* w2     = (const float*)d_in[10];
    const float* b2     = (const float*)d_in[11];
    const float* g2     = (const float*)d_in[12];
    const float* be2    = (const float*)d_in[13];

    float* skip  = (float*)d_out;
    float* xdown = skip + 16680960;          // 2*128*181*360

    float* ws       = (float*)d_ws;
    float* gn1_part = ws;                                   // [0, 4096)
    float* gn1_stat = ws + 4096;                            // [4096, 4128)
    float* gn2_part = ws + 4128;                            // [4128, 20512)  16384 f
    float* gn2_stat = ws + 20512;                           // [20512, 20544)
    unsigned short* wbf = (unsigned short*)(ws + 20544);    // 229376 us -> 135232
    unsigned short* w1f = (unsigned short*)(ws + 135232);   // 65536 us  -> 168000
    float*          b1f = ws + 168000;                      // 512 f     -> 168512
    unsigned short* w2b = (unsigned short*)(ws + 168512);   // 32768 us  -> 184896
    unsigned short* sbf = (unsigned short*)(ws + 184896);   // 16,680,960 us -> 8,525,376
    unsigned short* xdb = sbf;                              // overlay
    unsigned short* Yt  = (unsigned short*)(ws + 8525376);  // 29,352,960 us -> 23,201,856
    const size_t need = 23201856ull * 4ull;                 // ~92.8 MB

    const bool split = (ws_size >= need);

    k_prep       <<<2432, 256, 0, stream>>>(x, gn1_part, weight, wbf, w2, w2b);
    k_gn1_final  <<<16, 128, 0, stream>>>(gn1_part, gn1_stat);
    k_wfold      <<<512, 64, 0, stream>>>(w1, b1, gn1_stat, g1, be1, w1f, b1f);
    k_mlp        <<<dim3(1019, 2), 256, 0, stream>>>(x, w1f, b1f, w2b, b2,
                                                     skip, split ? sbf : (unsigned short*)nullptr);
    if (split){
        k_ybuild   <<<dim3(6, 91, 2), 256, 0, stream>>>(sbf, psi_v, psi_hi, psi_wi, Yt);
        k_dgemm    <<<dim3(256, 2, 2), 256, 0, stream>>>(Yt, wbf, bias, xdb, gn2_part);
        k_gn2_final_s<<<16, 256, 0, stream>>>(gn2_part, gn2_stat);
        k_gn2_apply_s<<<2048, 256, 0, stream>>>(xdb, xdown, gn2_stat, g2, be2);
    } else {
        k_disco_fb <<<dim3(2, 91, 4), 256, 0, stream>>>(skip, psi_v, psi_hi, psi_wi,
                                                        wbf, bias, xdown, gn2_part);
        k_gn2_final_fb<<<16, 256, 0, stream>>>(gn2_part, gn2_stat);
        k_gn2_apply<<<2048, 256, 0, stream>>>(xdown, gn2_stat, g2, be2);
    }
}

// Round 13
// 190.216 us; speedup vs baseline: 1.1916x; 1.1916x over previous
//
#include <hip/hip_runtime.h>

// DiscoDownBlock: GN1 -> 1x1 MLP (expand/gelu/project) + residual -> DISCO S2 conv
//                 -> GN2 -> gelu.  Outputs: skip [2,128,181,360], x_down [2,256,91,180]
//
// Round 13: surgical revert to R11 (best measured, 196us) + keep ONLY R12's
// k_prep launch merge. k_mlp back to launch_bounds(256,4) (R12's ,5 squeezed
// VGPR 64->48 and amplified sbf write traffic +45MB with no occupancy gain);
// k_dgemm back to 512-block version.

#define HW      65160      // 181*360
#define HIN     181
#define WIN     360
#define HOUT    91
#define WOUT    180
#define CIN     128
#define COUT    256
#define KB      7
#define NNZ     16
#define N_GN1   1042560    // 16*HW
#define N_GN2   524160     // 32*91*180
#define NPB     16380      // 91*180 (per-batch n)

typedef float  f32x4  __attribute__((ext_vector_type(4)));
typedef __bf16 bf16x8 __attribute__((ext_vector_type(8)));

__device__ __forceinline__ unsigned short f2b(float v){
    return __builtin_bit_cast(unsigned short, (__bf16)v);
}
__device__ __forceinline__ unsigned pkbf(float a, float b){
    return (unsigned)__builtin_bit_cast(unsigned short, (__bf16)a)
         | ((unsigned)__builtin_bit_cast(unsigned short, (__bf16)b) << 16);
}
__device__ __forceinline__ float blo(unsigned u){ return __uint_as_float(u << 16); }
__device__ __forceinline__ float bhi(unsigned u){ return __uint_as_float(u & 0xffff0000u); }

// gelu via sigmoid identity: 0.5v(1+tanh z) = v * sigma(2z).
__device__ __forceinline__ float gelu_f(float v){
    float z = v * __builtin_fmaf(0.0356774081363f, v*v, 0.7978845608028654f);
    float e = __builtin_amdgcn_exp2f(-2.8853900817779268f * z);
    return v * __builtin_amdgcn_rcpf(1.0f + e);
}

// ---------------- prep: GN1 partials + weight converts (merged) ----------------
// grid 2432 x 256: [0,2048) gn1_partial, [2048,2304) wcvt, [2304,2432) wcvt_w2.
__global__ __launch_bounds__(256) void k_prep(
    const float* __restrict__ x, float* __restrict__ part,
    const float* __restrict__ wsrc, unsigned short* __restrict__ wbf,
    const float* __restrict__ w2, unsigned short* __restrict__ w2b)
{
    const int blk_id = blockIdx.x;
    const int t = threadIdx.x;

    if (blk_id < 2048){
        const int bg = blk_id >> 7, blk = blk_id & 127;
        const float4* p4 = (const float4*)(x + (size_t)bg * N_GN1);
        float s = 0.f, ss = 0.f;
        for (int v = blk*256 + t; v < N_GN1/4; v += 128*256){
            float4 q = p4[v];
            s  += q.x + q.y + q.z + q.w;
            ss += q.x*q.x + q.y*q.y + q.z*q.z + q.w*q.w;
        }
        #pragma unroll
        for (int off = 32; off; off >>= 1){ s += __shfl_down(s, off); ss += __shfl_down(ss, off); }
        __shared__ float ls[4][2];
        if ((t & 63) == 0){ ls[t>>6][0] = s; ls[t>>6][1] = ss; }
        __syncthreads();
        if (t == 0){
            s  = ls[0][0] + ls[1][0] + ls[2][0] + ls[3][0];
            ss = ls[0][1] + ls[1][1] + ls[2][1] + ls[3][1];
            part[(bg*128 + blk)*2]     = s;
            part[(bg*128 + blk)*2 + 1] = ss;
        }
    } else if (blk_id < 2304){
        const int co = blk_id - 2048;
        for (int r = t; r < 896; r += 256){
            int k = r >> 7, c = r & 127;
            wbf[co*896 + r] = f2b(wsrc[co*896 + c*7 + k]);
        }
    } else {
        const int i = (blk_id - 2304)*256 + t;
        if (i < 32768) w2b[i] = f2b(w2[i]);
    }
}

__global__ __launch_bounds__(128) void k_gn1_final(const float* __restrict__ part,
                                                   float* __restrict__ stat){
    const int bg = blockIdx.x, t = threadIdx.x;
    float s  = part[(bg*128 + t)*2];
    float ss = part[(bg*128 + t)*2 + 1];
    #pragma unroll
    for (int off = 32; off; off >>= 1){ s += __shfl_down(s, off); ss += __shfl_down(ss, off); }
    __shared__ float ls[2][2];
    if ((t & 63) == 0){ ls[t>>6][0] = s; ls[t>>6][1] = ss; }
    __syncthreads();
    if (t == 0){
        s  = ls[0][0] + ls[1][0];
        ss = ls[0][1] + ls[1][1];
        float m = s / (float)N_GN1;
        float v = ss / (float)N_GN1 - m*m;
        stat[bg*2]     = m;
        stat[bg*2 + 1] = 1.0f / sqrtf(v + 1e-5f);
    }
}

// GN1 fold: w1f[b][oc][c] = bf16(w1[oc][c] * a[b][c]); b1f[b][oc] = b1[oc] + sum_c w1*bb
__global__ __launch_bounds__(64) void k_wfold(
    const float* __restrict__ w1, const float* __restrict__ b1,
    const float* __restrict__ stat, const float* __restrict__ g1,
    const float* __restrict__ be1,
    unsigned short* __restrict__ w1f, float* __restrict__ b1f)
{
    const int id = blockIdx.x;         // b*256 + oc
    const int b = id >> 8, oc = id & 255;
    const int l = threadIdx.x;
    float acc = 0.f;
    #pragma unroll
    for (int j = 0; j < 2; ++j){
        const int c = l + j*64;
        float m = stat[(b*8 + (c >> 4))*2];
        float r = stat[(b*8 + (c >> 4))*2 + 1];
        float a = r * g1[c];
        float bb = be1[c] - m*a;
        float wv = w1[oc*128 + c];
        w1f[((size_t)b*256 + oc)*128 + c] = f2b(wv * a);
        acc += wv * bb;
    }
    #pragma unroll
    for (int off = 32; off; off >>= 1) acc += __shfl_down(acc, off);
    if (l == 0) b1f[b*256 + oc] = b1[oc] + acc;
}

// ---------------- fused MLP + residual (MFMA, 2-half pipeline) ----------------
// grid (1019, 2), 256 thr (4 waves). 64-pixel tile.
// LDS: xns [64p][128c] raw-x bf16 16KB + h1h [64p][128 ocl] 16KB = 32KB.
__global__ __launch_bounds__(256, 4) void k_mlp(
    const float* __restrict__ x,
    const unsigned short* __restrict__ w1f, const float* __restrict__ b1f,
    const unsigned short* __restrict__ w2b, const float* __restrict__ b2,
    float* __restrict__ skip, unsigned short* __restrict__ sbf)
{
    __shared__ unsigned short xns[64*128];   // rows 256B, swizzled; raw x bf16
    __shared__ unsigned short h1h[64*128];   // rows 256B, swizzled (one oc-half)

    const int t = threadIdx.x;
    const int b = blockIdx.y;
    const int pix0 = blockIdx.x * 64;
    const int valid = min(64, HW - pix0);

    const int w  = t >> 6, l = t & 63;
    const int lr = l & 15, lk = l >> 4;

    { // stage raw x as bf16 (GN1 is folded into w1f/b1f)
        const int p = l;
        const unsigned sw = ((unsigned)(p & 7)) << 4;
        const float* xb = x + (size_t)b*128*HW + pix0 + p;
        #pragma unroll
        for (int i = 0; i < 8; ++i){
            const int c0 = w*32 + i*4;
            uint2 pk;
            if (p < valid){
                pk.x = pkbf(xb[(size_t)(c0+0)*HW], xb[(size_t)(c0+1)*HW]);
                pk.y = pkbf(xb[(size_t)(c0+2)*HW], xb[(size_t)(c0+3)*HW]);
            } else { pk.x = 0u; pk.y = 0u; }
            *(uint2*)((char*)xns + p*256 + (((unsigned)(c0*2)) ^ sw)) = pk;
        }
    }
    __syncthreads();

    // GEMM2 accumulator C[p][c]: pm 0..3 (p 16-blocks), cn 0..1 (c 16-blocks)
    f32x4 acc2[4][2];
    {
        const float bv0 = b2[w*32 + lr];
        const float bv1 = b2[w*32 + 16 + lr];
        #pragma unroll
        for (int pm = 0; pm < 4; ++pm){
            acc2[pm][0] = (f32x4)bv0;
            acc2[pm][1] = (f32x4)bv1;
        }
    }

    const unsigned short* w1p = w1f + (size_t)b*256*128;

    #pragma unroll
    for (int half = 0; half < 2; ++half){
        // ---- GEMM1 (this half): h1[ocl = w*32..+32][p], oc = half*128 + ocl ----
        {
            f32x4 acc1[2][4];
            #pragma unroll
            for (int m = 0; m < 2; ++m){
                float4 bv = *(const float4*)(b1f + b*256 + half*128 + w*32 + m*16 + lk*4);
                #pragma unroll
                for (int nf = 0; nf < 4; ++nf) acc1[m][nf] = __builtin_bit_cast(f32x4, bv);
            }
            const unsigned short* wr = w1p + (size_t)(half*128 + w*32 + lr)*128 + lk*8;
            #pragma unroll
            for (int ks = 0; ks < 4; ++ks){
                bf16x8 af[2];
                #pragma unroll
                for (int m = 0; m < 2; ++m)
                    af[m] = __builtin_bit_cast(bf16x8, *(const uint4*)(wr + m*16*128 + ks*32));
                bf16x8 bfv[4];
                #pragma unroll
                for (int nf = 0; nf < 4; ++nf){
                    const int p = nf*16 + lr;
                    unsigned off = (unsigned)(p*256)
                                 + (((unsigned)(ks*64 + lk*16)) ^ (((unsigned)(p & 7)) << 4));
                    bfv[nf] = __builtin_bit_cast(bf16x8, *(const uint4*)((const char*)xns + off));
                }
                #pragma unroll
                for (int m = 0; m < 2; ++m)
                    #pragma unroll
                    for (int nf = 0; nf < 4; ++nf)
                        acc1[m][nf] = __builtin_amdgcn_mfma_f32_16x16x32_bf16(af[m], bfv[nf], acc1[m][nf], 0, 0, 0);
            }
            // gelu + pack to h1h (local oc index)
            #pragma unroll
            for (int m = 0; m < 2; ++m){
                const int oc0 = w*32 + m*16 + lk*4;
                #pragma unroll
                for (int nf = 0; nf < 4; ++nf){
                    const int p = nf*16 + lr;
                    uint2 pk;
                    pk.x = pkbf(gelu_f(acc1[m][nf][0]), gelu_f(acc1[m][nf][1]));
                    pk.y = pkbf(gelu_f(acc1[m][nf][2]), gelu_f(acc1[m][nf][3]));
                    unsigned off = (unsigned)(p*256)
                                 + (((unsigned)(oc0*2)) ^ (((unsigned)(p & 7)) << 4));
                    *(uint2*)((char*)h1h + off) = pk;
                }
            }
        }
        __syncthreads();

        // ---- GEMM2 partial: accumulate K = this half's 128 oc ----
        {
            const unsigned short* wr = w2b + (size_t)(w*32 + lr)*256 + half*128 + lk*8;
            #pragma unroll
            for (int ks = 0; ks < 4; ++ks){
                bf16x8 bfw[2];
                #pragma unroll
                for (int cn = 0; cn < 2; ++cn)
                    bfw[cn] = __builtin_bit_cast(bf16x8, *(const uint4*)(wr + cn*16*256 + ks*32));
                bf16x8 afh[4];
                #pragma unroll
                for (int pm = 0; pm < 4; ++pm){
                    const int p = pm*16 + lr;
                    unsigned off = (unsigned)(p*256)
                                 + (((unsigned)(ks*64 + lk*16)) ^ (((unsigned)(p & 7)) << 4));
                    afh[pm] = __builtin_bit_cast(bf16x8, *(const uint4*)((const char*)h1h + off));
                }
                #pragma unroll
                for (int pm = 0; pm < 4; ++pm)
                    #pragma unroll
                    for (int cn = 0; cn < 2; ++cn)
                        acc2[pm][cn] = __builtin_amdgcn_mfma_f32_16x16x32_bf16(afh[pm], bfw[cn], acc2[pm][cn], 0, 0, 0);
            }
        }
        if (half == 0) __syncthreads();      // before G1b overwrites h1h
    }

    // ---- epilogue: residual from xns (raw-x bf16, still live); float4 skip
    //      stores; scalar u16 sbf stores ----
    #pragma unroll
    for (int pm = 0; pm < 4; ++pm){
        const int p0 = pm*16 + lk*4;
        if (p0 < valid){                     // valid is a multiple of 4 (tail = 8)
            #pragma unroll
            for (int cn = 0; cn < 2; ++cn){
                const int c = w*32 + cn*16 + lr;
                size_t base = (size_t)(b*128 + c)*HW + pix0 + p0;
                float4 o;
                #pragma unroll
                for (int r = 0; r < 4; ++r){
                    const int p = p0 + r;
                    unsigned off = (unsigned)(p*256)
                                 + (((unsigned)(c*2)) ^ (((unsigned)(p & 7)) << 4));
                    unsigned short us = *(const unsigned short*)((const char*)xns + off);
                    ((float*)&o)[r] = acc2[pm][cn][r] + blo((unsigned)us);
                }
                *(float4*)(skip + base) = o;
                if (sbf){
                    unsigned short* sp = sbf + ((size_t)b*HW + pix0 + p0)*128 + c;
                    sp[0]   = f2b(o.x);
                    sp[128] = f2b(o.y);
                    sp[256] = f2b(o.z);
                    sp[384] = f2b(o.w);
                }
            }
        }
    }
}

// ---------------- Y build: gather + psi reduce -> Y_t[n][ck] bf16 ----------------
// grid (6 wo-tiles of 32, 91 ho, 2 b), 256 thr = 32 wol x 8 cq.
__global__ __launch_bounds__(256) void k_ybuild(
    const unsigned short* __restrict__ sbf,
    const float* __restrict__ psi_v, const int* __restrict__ psi_hi, const int* __restrict__ psi_wi,
    unsigned short* __restrict__ Yt)
{
    __shared__ int   offh[16];
    __shared__ int   wis[16];
    __shared__ float psis[112];

    const int t   = threadIdx.x;
    const int wot = blockIdx.x, ho = blockIdx.y, b = blockIdx.z;

    if (t < 112) psis[t] = psi_v[((t >> 4)*HOUT + ho)*NNZ + (t & 15)];
    if (t < 16){ offh[t] = psi_hi[ho*NNZ + t] * WIN; wis[t] = psi_wi[ho*NNZ + t]; }
    __syncthreads();

    const int wol = t >> 3, cq = t & 7;
    const int wo  = wot*32 + wol;
    const bool valid = (wo < WOUT);
    const int wo_c = valid ? wo : (WOUT - 1);

    int offs[16];
    #pragma unroll
    for (int n = 0; n < 16; ++n){
        int wv = wis[n] + 2*wo_c;
        wv = (wv >= WIN) ? (wv - WIN) : wv;
        offs[n] = offh[n] + wv;
    }

    const unsigned short* sb = sbf + (size_t)b * HW * 128;
    unsigned short* yrow = Yt + (size_t)(b*NPB + ho*WOUT + wo_c) * 896;

    #pragma unroll 1
    for (int cc = 0; cc < 4; ++cc){
        const int c0 = cc*32 + cq*4;
        float ya[4][7];
        #pragma unroll
        for (int ci = 0; ci < 4; ++ci)
            #pragma unroll
            for (int k = 0; k < 7; ++k) ya[ci][k] = 0.f;

        #pragma unroll 2
        for (int n = 0; n < 16; ++n){
            uint2 q = *(const uint2*)(sb + (size_t)offs[n]*128 + c0);
            float g0 = blo(q.x), g1 = bhi(q.x), g2 = blo(q.y), g3 = bhi(q.y);
            #pragma unroll
            for (int k = 0; k < 7; ++k){
                float pv = psis[k*16 + n];
                ya[0][k] += pv*g0; ya[1][k] += pv*g1;
                ya[2][k] += pv*g2; ya[3][k] += pv*g3;
            }
        }
        if (valid){
            #pragma unroll
            for (int k = 0; k < 7; ++k){
                uint2 pk;
                pk.x = pkbf(ya[0][k], ya[1][k]);
                pk.y = pkbf(ya[2][k], ya[3][k]);
                *(uint2*)(yrow + k*128 + c0) = pk;
            }
        }
    }
}

// ---------------- DISCO GEMM: D[n][co] = Y_t @ W^T, no LDS ----------------
// grid 512 blocks (XCD-swizzled), 256 thr (4 waves, 64n x 64co each).
__global__ __launch_bounds__(256) void k_dgemm(
    const unsigned short* __restrict__ Yt, const unsigned short* __restrict__ wbf,
    const float* __restrict__ bias,
    unsigned short* __restrict__ xdb, float* __restrict__ part)
{
    const int flat = blockIdx.x + 128*(blockIdx.y + 2*blockIdx.z);
    const int rem  = (flat & 7)*64 + (flat >> 3);
    const int coh  = rem & 1;
    const int nt   = (rem >> 1) & 127;
    const int b    = rem >> 8;

    const int t = threadIdx.x;
    const int w = t >> 6, l = t & 63;
    const int lr = l & 15, lk = l >> 4;
    const int wn2 = w >> 1, wc = w & 1;

    const int n0  = nt*128 + wn2*64;
    const int co0 = coh*128 + wc*64;

    const unsigned short* pa[4];
    const unsigned short* pb[4];
    #pragma unroll
    for (int i = 0; i < 4; ++i)
        pa[i] = Yt + (size_t)(b*NPB + n0 + i*16 + lr)*896 + lk*8;
    #pragma unroll
    for (int j = 0; j < 4; ++j)
        pb[j] = wbf + (size_t)(co0 + j*16 + lr)*896 + lk*8;

    f32x4 acc[4][4];
    #pragma unroll
    for (int i = 0; i < 4; ++i)
        #pragma unroll
        for (int j = 0; j < 4; ++j) acc[i][j] = (f32x4)0.f;

    #pragma unroll 2
    for (int ks = 0; ks < 28; ++ks){
        bf16x8 af[4], bf[4];
        #pragma unroll
        for (int i = 0; i < 4; ++i)
            af[i] = __builtin_bit_cast(bf16x8, *(const uint4*)(pa[i] + ks*32));
        #pragma unroll
        for (int j = 0; j < 4; ++j)
            bf[j] = __builtin_bit_cast(bf16x8, *(const uint4*)(pb[j] + ks*32));
        #pragma unroll
        for (int i = 0; i < 4; ++i)
            #pragma unroll
            for (int j = 0; j < 4; ++j)
                acc[i][j] = __builtin_amdgcn_mfma_f32_16x16x32_bf16(af[i], bf[j], acc[i][j], 0, 0, 0);
    }

    float s[2] = {0.f, 0.f}, ss[2] = {0.f, 0.f};
    #pragma unroll
    for (int j = 0; j < 4; ++j){
        const int co = co0 + j*16 + lr;
        const float bv = bias[co];
        unsigned short* outp = xdb + (size_t)(b*256 + co)*NPB;
        const int jp = j >> 1;
        #pragma unroll
        for (int i = 0; i < 4; ++i){
            const int nb = n0 + i*16 + lk*4;
            if (nb < NPB){
                float o0 = acc[i][j][0] + bv, o1 = acc[i][j][1] + bv;
                float o2 = acc[i][j][2] + bv, o3 = acc[i][j][3] + bv;
                uint2 pk; pk.x = pkbf(o0, o1); pk.y = pkbf(o2, o3);
                *(uint2*)(outp + nb) = pk;
                s[jp]  += o0 + o1 + o2 + o3;
                ss[jp] += o0*o0 + o1*o1 + o2*o2 + o3*o3;
            }
        }
    }
    #pragma unroll
    for (int off = 32; off; off >>= 1){
        s[0] += __shfl_down(s[0], off); ss[0] += __shfl_down(ss[0], off);
        s[1] += __shfl_down(s[1], off); ss[1] += __shfl_down(ss[1], off);
    }
    if (l == 0){
        const int bid = (b*2 + coh)*128 + nt;
        part[(bid*8 + w*2 + 0)*2]     = s[0];
        part[(bid*8 + w*2 + 0)*2 + 1] = ss[0];
        part[(bid*8 + w*2 + 1)*2]     = s[1];
        part[(bid*8 + w*2 + 1)*2 + 1] = ss[1];
    }
}

// ---------------- GN2 finalize (split path) ----------------
__global__ __launch_bounds__(256) void k_gn2_final_s(const float* __restrict__ part,
                                                     float* __restrict__ stat){
    const int bg = blockIdx.x, b = bg >> 3, g = bg & 7, t = threadIdx.x;
    const int coh = g >> 2, wc = (g >> 1) & 1, jp = g & 1;
    const int nt = t & 127, wn2 = t >> 7;
    const int bid = (b*2 + coh)*128 + nt;
    const int slot = (wn2*2 + wc)*2 + jp;
    float s  = part[(bid*8 + slot)*2];
    float ss = part[(bid*8 + slot)*2 + 1];
    #pragma unroll
    for (int off = 32; off; off >>= 1){ s += __shfl_down(s, off); ss += __shfl_down(ss, off); }
    __shared__ float ls[4][2];
    if ((t & 63) == 0){ ls[t>>6][0] = s; ls[t>>6][1] = ss; }
    __syncthreads();
    if (t == 0){
        s  = ls[0][0] + ls[1][0] + ls[2][0] + ls[3][0];
        ss = ls[0][1] + ls[1][1] + ls[2][1] + ls[3][1];
        float m = s / (float)N_GN2;
        float v = ss / (float)N_GN2 - m*m;
        stat[bg*2]     = m;
        stat[bg*2 + 1] = 1.0f / sqrtf(v + 1e-5f);
    }
}

// ---------------- GN2 apply + gelu: bf16 in -> fp32 out (split path) ----------------
__global__ __launch_bounds__(256) void k_gn2_apply_s(const unsigned short* __restrict__ xdb,
                                                     float* __restrict__ outd,
                                                     const float* __restrict__ stat,
                                                     const float* __restrict__ g2a,
                                                     const float* __restrict__ be2){
    const int gid = blockIdx.x*256 + threadIdx.x;
    const int stride = gridDim.x*256;
    for (int v = gid; v < 2096640; v += stride){
        uint2 q = ((const uint2*)xdb)[v];
        int i  = v << 2;
        int bc = i / 16380;
        int co = bc & 255, b = bc >> 8;
        float m  = stat[(b*8 + (co >> 5))*2];
        float r  = stat[(b*8 + (co >> 5))*2 + 1];
        float a  = r * g2a[co];
        float bb = be2[co] - m*a;
        float4 o;
        o.x = gelu_f(__builtin_fmaf(blo(q.x), a, bb));
        o.y = gelu_f(__builtin_fmaf(bhi(q.x), a, bb));
        o.z = gelu_f(__builtin_fmaf(blo(q.y), a, bb));
        o.w = gelu_f(__builtin_fmaf(bhi(q.y), a, bb));
        ((float4*)outd)[v] = o;
    }
}

// ================= FALLBACK (fused disco, fp32 in-place apply) =================
__global__ __launch_bounds__(256, 2) void k_disco_fb(
    const float* __restrict__ skip,
    const float* __restrict__ psi_v, const int* __restrict__ psi_hi, const int* __restrict__ psi_wi,
    const unsigned short* __restrict__ wbf, const float* __restrict__ bias,
    float* __restrict__ xdown, float* __restrict__ part)
{
    __shared__ unsigned short yT[96*256];

    const int t   = threadIdx.x;
    const int woh = blockIdx.x;
    const int ho  = blockIdx.y;
    const int z   = blockIdx.z;
    const int b   = z >> 1, coh = z & 1;
    const int co0 = coh * 128;
    const int wo0 = woh * 90;

    const int w  = t >> 6;
    const int l  = t & 63;
    const int wm = w >> 1, wn = w & 1;

    const int wol = t & 31;
    const int cq  = t >> 5;
    const unsigned sw = (unsigned)(wol & 7) << 4;

    const float* skipb = skip + (size_t)b * (128*HW);

    f32x4 acc[4][3];
    #pragma unroll
    for (int m = 0; m < 4; ++m)
        #pragma unroll
        for (int nf = 0; nf < 3; ++nf) acc[m][nf] = (f32x4)0.f;

    #pragma unroll 1
    for (int cc = 0; cc < 4; ++cc){
        __syncthreads();
        const float* bp0 = skipb + (size_t)(cc*32 + cq*4 + 0)*HW;
        const float* bp1 = skipb + (size_t)(cc*32 + cq*4 + 1)*HW;
        const float* bp2 = skipb + (size_t)(cc*32 + cq*4 + 2)*HW;
        const float* bp3 = skipb + (size_t)(cc*32 + cq*4 + 3)*HW;

        float ya[3][4][7];
        #pragma unroll
        for (int wj = 0; wj < 3; ++wj)
            #pragma unroll
            for (int ci = 0; ci < 4; ++ci)
                #pragma unroll
                for (int k = 0; k < 7; ++k) ya[wj][ci][k] = 0.f;

        #pragma unroll 2
        for (int n = 0; n < NNZ; ++n){
            const int hi = psi_hi[ho*NNZ + n];
            const int wi = psi_wi[ho*NNZ + n];
            float ps[7];
            #pragma unroll
            for (int k = 0; k < 7; ++k) ps[k] = psi_v[(k*HOUT + ho)*NNZ + n];
            const int rowb = hi * WIN;
            #pragma unroll
            for (int wj = 0; wj < 3; ++wj){
                int wv = wi + 2*(wo0 + wol + 32*wj);
                wv = (wv >= 720) ? (wv - 720) : (wv >= 360 ? (wv - 360) : wv);
                const int off = rowb + wv;
                float g0 = bp0[off], g1 = bp1[off], g2 = bp2[off], g3 = bp3[off];
                #pragma unroll
                for (int k = 0; k < 7; ++k){
                    float pv = ps[k];
                    ya[wj][0][k] += pv*g0; ya[wj][1][k] += pv*g1;
                    ya[wj][2][k] += pv*g2; ya[wj][3][k] += pv*g3;
                }
            }
        }
        #pragma unroll
        for (int wj = 0; wj < 3; ++wj){
            char* row = (char*)yT + (wol + 32*wj)*512;
            #pragma unroll
            for (int k = 0; k < 7; ++k){
                unsigned base = ((unsigned)(k*64 + cq*8)) ^ sw;
                *(unsigned*)(row + base)     = pkbf(ya[wj][0][k], ya[wj][1][k]);
                *(unsigned*)(row + base + 4) = pkbf(ya[wj][2][k], ya[wj][3][k]);
            }
        }
        __syncthreads();

        const unsigned short* wrow = wbf + (size_t)(co0 + wm*64 + (l & 15))*896
                                         + cc*32 + ((l >> 4) << 3);
        #pragma unroll
        for (int k = 0; k < 7; ++k){
            bf16x8 af[4];
            #pragma unroll
            for (int m = 0; m < 4; ++m)
                af[m] = __builtin_bit_cast(bf16x8,
                          *(const uint4*)(wrow + (size_t)m*16*896 + k*128));
            bf16x8 bfv[3];
            #pragma unroll
            for (int nf = 0; nf < 3; ++nf){
                const int wo_l = wn*48 + nf*16 + (l & 15);
                unsigned off = (unsigned)(wo_l*512)
                             + (((unsigned)(k*64) + ((unsigned)(l >> 4) << 4))
                                ^ ((unsigned)(wo_l & 7) << 4));
                bfv[nf] = __builtin_bit_cast(bf16x8, *(const uint4*)((const char*)yT + off));
            }
            #pragma unroll
            for (int m = 0; m < 4; ++m)
                #pragma unroll
                for (int nf = 0; nf < 3; ++nf)
                    acc[m][nf] = __builtin_amdgcn_mfma_f32_16x16x32_bf16(af[m], bfv[nf], acc[m][nf], 0, 0, 0);
        }
    }

    float s[2] = {0.f, 0.f}, ss[2] = {0.f, 0.f};
    #pragma unroll
    for (int m = 0; m < 4; ++m){
        const int pair = m >> 1;
        const int cob = co0 + wm*64 + m*16 + ((l >> 4) << 2);
        float4 bv = *(const float4*)(bias + cob);
        #pragma unroll
        for (int nf = 0; nf < 3; ++nf){
            const int wo_t = wn*48 + nf*16 + (l & 15);
            if (wo_t < 90){
                #pragma unroll
                for (int r = 0; r < 4; ++r){
                    float v = acc[m][nf][r] + ((const float*)&bv)[r];
                    xdown[((size_t)(b*256 + cob + r)*HOUT + ho)*WOUT + wo0 + wo_t] = v;
                    s[pair] += v; ss[pair] += v*v;
                }
            }
        }
    }
    #pragma unroll
    for (int off = 32; off; off >>= 1){
        s[0] += __shfl_down(s[0], off); ss[0] += __shfl_down(ss[0], off);
        s[1] += __shfl_down(s[1], off); ss[1] += __shfl_down(ss[1], off);
    }
    if (l == 0){
        const int tid = (z*91 + ho)*2 + woh;
        part[(tid*8 + w*2 + 0)*2]     = s[0];
        part[(tid*8 + w*2 + 0)*2 + 1] = ss[0];
        part[(tid*8 + w*2 + 1)*2]     = s[1];
        part[(tid*8 + w*2 + 1)*2 + 1] = ss[1];
    }
}

__global__ __launch_bounds__(256) void k_gn2_final_fb(const float* __restrict__ part,
                                                      float* __restrict__ stat){
    const int bg = blockIdx.x, b = bg >> 3, g = bg & 7, t = threadIdx.x;
    const int coh = g >> 2, gl = g & 3, wm = gl >> 1, pair = gl & 1;
    float s = 0.f, ss = 0.f;
    for (int i = t; i < 364; i += 256){
        int ho = i >> 2, r = i & 3, woh = r >> 1, wn = r & 1;
        int tid = (((b*2 + coh)*91 + ho)*2 + woh);
        int slot = (wm*2 + wn)*2 + pair;
        s  += part[(tid*8 + slot)*2];
        ss += part[(tid*8 + slot)*2 + 1];
    }
    #pragma unroll
    for (int off = 32; off; off >>= 1){ s += __shfl_down(s, off); ss += __shfl_down(ss, off); }
    __shared__ float ls[4][2];
    if ((t & 63) == 0){ ls[t>>6][0] = s; ls[t>>6][1] = ss; }
    __syncthreads();
    if (t == 0){
        s  = ls[0][0] + ls[1][0] + ls[2][0] + ls[3][0];
        ss = ls[0][1] + ls[1][1] + ls[2][1] + ls[3][1];
        float m = s / (float)N_GN2;
        float v = ss / (float)N_GN2 - m*m;
        stat[bg*2]     = m;
        stat[bg*2 + 1] = 1.0f / sqrtf(v + 1e-5f);
    }
}

__global__ __launch_bounds__(256) void k_gn2_apply(float* __restrict__ xd,
                                                   const float* __restrict__ stat,
                                                   const float* __restrict__ g2a,
                                                   const float* __restrict__ be2){
    const int gid = blockIdx.x*256 + threadIdx.x;
    const int stride = gridDim.x*256;
    for (int v = gid; v < 2096640; v += stride){
        float4 q = ((float4*)xd)[v];
        int i  = v << 2;
        int bc = i / 16380;
        int co = bc & 255, b = bc >> 8;
        float m  = stat[(b*8 + (co >> 5))*2];
        float r  = stat[(b*8 + (co >> 5))*2 + 1];
        float a  = r * g2a[co];
        float bb = be2[co] - m*a;
        q.x = gelu_f(__builtin_fmaf(q.x, a, bb));
        q.y = gelu_f(__builtin_fmaf(q.y, a, bb));
        q.z = gelu_f(__builtin_fmaf(q.z, a, bb));
        q.w = gelu_f(__builtin_fmaf(q.w, a, bb));
        ((float4*)xd)[v] = q;
    }
}

extern "C" void kernel_launch(void* const* d_in, const int* in_sizes, int n_in,
                              void* d_out, int out_size, void* d_ws, size_t ws_size,
                              hipStream_t stream){
    const float* x      = (const float*)d_in[0];
    const float* psi_v  = (const float*)d_in[1];
    const int*   psi_hi = (const int*)d_in[2];
    const int*   psi_wi = (const int*)d_in[3];
    const float* weight = (const float*)d_in[4];
    const float* bias   = (const float*)d_in[5];
    const float* g1     = (const float*)d_in[6];
    const float* be1    = (const float*)d_in[7];
    const float* w1     = (const float*)d_in[8];
    const float* b1     = (const float*)d_in[9];
    const float* w2     = (const float*)d_in[10];
    const float* b2     = (const float*)d_in[11];
    const float* g2     = (const float*)d_in[12];
    const float* be2    = (const float*)d_in[13];

    float* skip  = (float*)d_out;
    float* xdown = skip + 16680960;          // 2*128*181*360

    float* ws       = (float*)d_ws;
    float* gn1_part = ws;                                   // 4096 f
    float* gn1_stat = ws + 4096;                            // 32 f
    float* gn2_part = ws + 4128;                            // 11648 f
    float* gn2_stat = ws + 15776;                           // 32 f
    unsigned short* wbf = (unsigned short*)(ws + 15808);    // 229376 us -> 130496
    unsigned short* w1f = (unsigned short*)(ws + 130496);   // 65536 us  -> 163264
    float*          b1f = ws + 163264;                      // 512 f     -> 163776
    unsigned short* w2b = (unsigned short*)(ws + 163776);   // 32768 us  -> 180160
    unsigned short* sbf = (unsigned short*)(ws + 180160);   // 16,680,960 us -> 8,520,640
    unsigned short* xdb = sbf;                              // overlay
    unsigned short* Yt  = (unsigned short*)(ws + 8520640);  // 29,352,960 us -> 23,197,120
    const size_t need = 23197120ull * 4ull;                 // ~92.79 MB

    const bool split = (ws_size >= need);

    k_prep       <<<2432, 256, 0, stream>>>(x, gn1_part, weight, wbf, w2, w2b);
    k_gn1_final  <<<16, 128, 0, stream>>>(gn1_part, gn1_stat);
    k_wfold      <<<512, 64, 0, stream>>>(w1, b1, gn1_stat, g1, be1, w1f, b1f);
    k_mlp        <<<dim3(1019, 2), 256, 0, stream>>>(x, w1f, b1f, w2b, b2,
                                                     skip, split ? sbf : (unsigned short*)nullptr);
    if (split){
        k_ybuild   <<<dim3(6, 91, 2), 256, 0, stream>>>(sbf, psi_v, psi_hi, psi_wi, Yt);
        k_dgemm    <<<dim3(128, 2, 2), 256, 0, stream>>>(Yt, wbf, bias, xdb, gn2_part);
        k_gn2_final_s<<<16, 256, 0, stream>>>(gn2_part, gn2_stat);
        k_gn2_apply_s<<<2048, 256, 0, stream>>>(xdb, xdown, gn2_stat, g2, be2);
    } else {
        k_disco_fb <<<dim3(2, 91, 4), 256, 0, stream>>>(skip, psi_v, psi_hi, psi_wi,
                                                        wbf, bias, xdown, gn2_part);
        k_gn2_final_fb<<<16, 256, 0, stream>>>(gn2_part, gn2_stat);
        k_gn2_apply<<<2048, 256, 0, stream>>>(xdown, gn2_stat, g2, be2);
    }
}

// Round 14
// 177.201 us; speedup vs baseline: 1.2791x; 1.0734x over previous
//
#include <hip/hip_runtime.h>

// DiscoDownBlock: GN1 -> 1x1 MLP (expand/gelu/project) + residual -> DISCO S2 conv
//                 -> GN2 -> gelu.  Outputs: skip [2,128,181,360], x_down [2,256,91,180]
//
// Round 14 (on R13 base, 190us):
//  - k_ybuild remapped 16wo x 16cq with uint4 loads/stores: one pass over all
//    128 channels (was 4 passes of uint2) -> 4x fewer memory ops.
//  - k_fold merges gn1_final + wfold (redundant per-block stat reduction,
//    L2-hot): one less serialized launch.
//  - k_mlp / k_dgemm / rest byte-identical to R13.

#define HW      65160      // 181*360
#define HIN     181
#define WIN     360
#define HOUT    91
#define WOUT    180
#define CIN     128
#define COUT    256
#define KB      7
#define NNZ     16
#define N_GN1   1042560    // 16*HW
#define N_GN2   524160     // 32*91*180
#define NPB     16380      // 91*180 (per-batch n)

typedef float  f32x4  __attribute__((ext_vector_type(4)));
typedef __bf16 bf16x8 __attribute__((ext_vector_type(8)));

__device__ __forceinline__ unsigned short f2b(float v){
    return __builtin_bit_cast(unsigned short, (__bf16)v);
}
__device__ __forceinline__ unsigned pkbf(float a, float b){
    return (unsigned)__builtin_bit_cast(unsigned short, (__bf16)a)
         | ((unsigned)__builtin_bit_cast(unsigned short, (__bf16)b) << 16);
}
__device__ __forceinline__ float blo(unsigned u){ return __uint_as_float(u << 16); }
__device__ __forceinline__ float bhi(unsigned u){ return __uint_as_float(u & 0xffff0000u); }

// gelu via sigmoid identity: 0.5v(1+tanh z) = v * sigma(2z).
__device__ __forceinline__ float gelu_f(float v){
    float z = v * __builtin_fmaf(0.0356774081363f, v*v, 0.7978845608028654f);
    float e = __builtin_amdgcn_exp2f(-2.8853900817779268f * z);
    return v * __builtin_amdgcn_rcpf(1.0f + e);
}

// ---------------- prep: GN1 partials + weight converts (merged) ----------------
// grid 2432 x 256: [0,2048) gn1_partial, [2048,2304) wcvt, [2304,2432) wcvt_w2.
__global__ __launch_bounds__(256) void k_prep(
    const float* __restrict__ x, float* __restrict__ part,
    const float* __restrict__ wsrc, unsigned short* __restrict__ wbf,
    const float* __restrict__ w2, unsigned short* __restrict__ w2b)
{
    const int blk_id = blockIdx.x;
    const int t = threadIdx.x;

    if (blk_id < 2048){
        const int bg = blk_id >> 7, blk = blk_id & 127;
        const float4* p4 = (const float4*)(x + (size_t)bg * N_GN1);
        float s = 0.f, ss = 0.f;
        for (int v = blk*256 + t; v < N_GN1/4; v += 128*256){
            float4 q = p4[v];
            s  += q.x + q.y + q.z + q.w;
            ss += q.x*q.x + q.y*q.y + q.z*q.z + q.w*q.w;
        }
        #pragma unroll
        for (int off = 32; off; off >>= 1){ s += __shfl_down(s, off); ss += __shfl_down(ss, off); }
        __shared__ float ls[4][2];
        if ((t & 63) == 0){ ls[t>>6][0] = s; ls[t>>6][1] = ss; }
        __syncthreads();
        if (t == 0){
            s  = ls[0][0] + ls[1][0] + ls[2][0] + ls[3][0];
            ss = ls[0][1] + ls[1][1] + ls[2][1] + ls[3][1];
            part[(bg*128 + blk)*2]     = s;
            part[(bg*128 + blk)*2 + 1] = ss;
        }
    } else if (blk_id < 2304){
        const int co = blk_id - 2048;
        for (int r = t; r < 896; r += 256){
            int k = r >> 7, c = r & 127;
            wbf[co*896 + r] = f2b(wsrc[co*896 + c*7 + k]);
        }
    } else {
        const int i = (blk_id - 2304)*256 + t;
        if (i < 32768) w2b[i] = f2b(w2[i]);
    }
}

// ---------------- fold: GN1 finalize (redundant per block) + w1 fold ----------------
// grid 512 (b*256+oc), 64 thr.  Stats reduced from partials (L2-hot).
__global__ __launch_bounds__(64) void k_fold(
    const float* __restrict__ part,
    const float* __restrict__ w1, const float* __restrict__ b1,
    const float* __restrict__ g1, const float* __restrict__ be1,
    unsigned short* __restrict__ w1f, float* __restrict__ b1f)
{
    const int id = blockIdx.x;         // b*256 + oc
    const int b = id >> 8, oc = id & 255;
    const int l = threadIdx.x;

    float mArr[8], rArr[8];
    #pragma unroll
    for (int g = 0; g < 8; ++g){
        const int bg = b*8 + g;
        float s  = part[(bg*128 + l)*2]     + part[(bg*128 + 64 + l)*2];
        float ss = part[(bg*128 + l)*2 + 1] + part[(bg*128 + 64 + l)*2 + 1];
        #pragma unroll
        for (int off = 32; off; off >>= 1){ s += __shfl_down(s, off); ss += __shfl_down(ss, off); }
        s = __shfl(s, 0); ss = __shfl(ss, 0);
        float m = s / (float)N_GN1;
        float v = ss / (float)N_GN1 - m*m;
        mArr[g] = m;
        rArr[g] = 1.0f / sqrtf(v + 1e-5f);
    }

    float acc = 0.f;
    #pragma unroll
    for (int j = 0; j < 2; ++j){
        const int c = l + j*64;
        const int g = c >> 4;
        float a  = rArr[g] * g1[c];
        float bb = be1[c] - mArr[g]*a;
        float wv = w1[oc*128 + c];
        w1f[((size_t)b*256 + oc)*128 + c] = f2b(wv * a);
        acc += wv * bb;
    }
    #pragma unroll
    for (int off = 32; off; off >>= 1) acc += __shfl_down(acc, off);
    if (l == 0) b1f[b*256 + oc] = b1[oc] + acc;
}

// ---------------- fused MLP + residual (MFMA, 2-half pipeline) ----------------
// grid (1019, 2), 256 thr (4 waves). 64-pixel tile.
// LDS: xns [64p][128c] raw-x bf16 16KB + h1h [64p][128 ocl] 16KB = 32KB.
__global__ __launch_bounds__(256, 4) void k_mlp(
    const float* __restrict__ x,
    const unsigned short* __restrict__ w1f, const float* __restrict__ b1f,
    const unsigned short* __restrict__ w2b, const float* __restrict__ b2,
    float* __restrict__ skip, unsigned short* __restrict__ sbf)
{
    __shared__ unsigned short xns[64*128];   // rows 256B, swizzled; raw x bf16
    __shared__ unsigned short h1h[64*128];   // rows 256B, swizzled (one oc-half)

    const int t = threadIdx.x;
    const int b = blockIdx.y;
    const int pix0 = blockIdx.x * 64;
    const int valid = min(64, HW - pix0);

    const int w  = t >> 6, l = t & 63;
    const int lr = l & 15, lk = l >> 4;

    { // stage raw x as bf16 (GN1 is folded into w1f/b1f)
        const int p = l;
        const unsigned sw = ((unsigned)(p & 7)) << 4;
        const float* xb = x + (size_t)b*128*HW + pix0 + p;
        #pragma unroll
        for (int i = 0; i < 8; ++i){
            const int c0 = w*32 + i*4;
            uint2 pk;
            if (p < valid){
                pk.x = pkbf(xb[(size_t)(c0+0)*HW], xb[(size_t)(c0+1)*HW]);
                pk.y = pkbf(xb[(size_t)(c0+2)*HW], xb[(size_t)(c0+3)*HW]);
            } else { pk.x = 0u; pk.y = 0u; }
            *(uint2*)((char*)xns + p*256 + (((unsigned)(c0*2)) ^ sw)) = pk;
        }
    }
    __syncthreads();

    // GEMM2 accumulator C[p][c]: pm 0..3 (p 16-blocks), cn 0..1 (c 16-blocks)
    f32x4 acc2[4][2];
    {
        const float bv0 = b2[w*32 + lr];
        const float bv1 = b2[w*32 + 16 + lr];
        #pragma unroll
        for (int pm = 0; pm < 4; ++pm){
            acc2[pm][0] = (f32x4)bv0;
            acc2[pm][1] = (f32x4)bv1;
        }
    }

    const unsigned short* w1p = w1f + (size_t)b*256*128;

    #pragma unroll
    for (int half = 0; half < 2; ++half){
        // ---- GEMM1 (this half): h1[ocl = w*32..+32][p], oc = half*128 + ocl ----
        {
            f32x4 acc1[2][4];
            #pragma unroll
            for (int m = 0; m < 2; ++m){
                float4 bv = *(const float4*)(b1f + b*256 + half*128 + w*32 + m*16 + lk*4);
                #pragma unroll
                for (int nf = 0; nf < 4; ++nf) acc1[m][nf] = __builtin_bit_cast(f32x4, bv);
            }
            const unsigned short* wr = w1p + (size_t)(half*128 + w*32 + lr)*128 + lk*8;
            #pragma unroll
            for (int ks = 0; ks < 4; ++ks){
                bf16x8 af[2];
                #pragma unroll
                for (int m = 0; m < 2; ++m)
                    af[m] = __builtin_bit_cast(bf16x8, *(const uint4*)(wr + m*16*128 + ks*32));
                bf16x8 bfv[4];
                #pragma unroll
                for (int nf = 0; nf < 4; ++nf){
                    const int p = nf*16 + lr;
                    unsigned off = (unsigned)(p*256)
                                 + (((unsigned)(ks*64 + lk*16)) ^ (((unsigned)(p & 7)) << 4));
                    bfv[nf] = __builtin_bit_cast(bf16x8, *(const uint4*)((const char*)xns + off));
                }
                #pragma unroll
                for (int m = 0; m < 2; ++m)
                    #pragma unroll
                    for (int nf = 0; nf < 4; ++nf)
                        acc1[m][nf] = __builtin_amdgcn_mfma_f32_16x16x32_bf16(af[m], bfv[nf], acc1[m][nf], 0, 0, 0);
            }
            // gelu + pack to h1h (local oc index)
            #pragma unroll
            for (int m = 0; m < 2; ++m){
                const int oc0 = w*32 + m*16 + lk*4;
                #pragma unroll
                for (int nf = 0; nf < 4; ++nf){
                    const int p = nf*16 + lr;
                    uint2 pk;
                    pk.x = pkbf(gelu_f(acc1[m][nf][0]), gelu_f(acc1[m][nf][1]));
                    pk.y = pkbf(gelu_f(acc1[m][nf][2]), gelu_f(acc1[m][nf][3]));
                    unsigned off = (unsigned)(p*256)
                                 + (((unsigned)(oc0*2)) ^ (((unsigned)(p & 7)) << 4));
                    *(uint2*)((char*)h1h + off) = pk;
                }
            }
        }
        __syncthreads();

        // ---- GEMM2 partial: accumulate K = this half's 128 oc ----
        {
            const unsigned short* wr = w2b + (size_t)(w*32 + lr)*256 + half*128 + lk*8;
            #pragma unroll
            for (int ks = 0; ks < 4; ++ks){
                bf16x8 bfw[2];
                #pragma unroll
                for (int cn = 0; cn < 2; ++cn)
                    bfw[cn] = __builtin_bit_cast(bf16x8, *(const uint4*)(wr + cn*16*256 + ks*32));
                bf16x8 afh[4];
                #pragma unroll
                for (int pm = 0; pm < 4; ++pm){
                    const int p = pm*16 + lr;
                    unsigned off = (unsigned)(p*256)
                                 + (((unsigned)(ks*64 + lk*16)) ^ (((unsigned)(p & 7)) << 4));
                    afh[pm] = __builtin_bit_cast(bf16x8, *(const uint4*)((const char*)h1h + off));
                }
                #pragma unroll
                for (int pm = 0; pm < 4; ++pm)
                    #pragma unroll
                    for (int cn = 0; cn < 2; ++cn)
                        acc2[pm][cn] = __builtin_amdgcn_mfma_f32_16x16x32_bf16(afh[pm], bfw[cn], acc2[pm][cn], 0, 0, 0);
            }
        }
        if (half == 0) __syncthreads();      // before G1b overwrites h1h
    }

    // ---- epilogue: residual from xns (raw-x bf16, still live); float4 skip
    //      stores; scalar u16 sbf stores ----
    #pragma unroll
    for (int pm = 0; pm < 4; ++pm){
        const int p0 = pm*16 + lk*4;
        if (p0 < valid){                     // valid is a multiple of 4 (tail = 8)
            #pragma unroll
            for (int cn = 0; cn < 2; ++cn){
                const int c = w*32 + cn*16 + lr;
                size_t base = (size_t)(b*128 + c)*HW + pix0 + p0;
                float4 o;
                #pragma unroll
                for (int r = 0; r < 4; ++r){
                    const int p = p0 + r;
                    unsigned off = (unsigned)(p*256)
                                 + (((unsigned)(c*2)) ^ (((unsigned)(p & 7)) << 4));
                    unsigned short us = *(const unsigned short*)((const char*)xns + off);
                    ((float*)&o)[r] = acc2[pm][cn][r] + blo((unsigned)us);
                }
                *(float4*)(skip + base) = o;
                if (sbf){
                    unsigned short* sp = sbf + ((size_t)b*HW + pix0 + p0)*128 + c;
                    sp[0]   = f2b(o.x);
                    sp[128] = f2b(o.y);
                    sp[256] = f2b(o.z);
                    sp[384] = f2b(o.w);
                }
            }
        }
    }
}

// ---------------- Y build: gather + psi reduce -> Y_t[n][ck] bf16 ----------------
// grid (12 wo-tiles of 16, 91 ho, 2 b), 256 thr = 16 wol x 16 cq; uint4 I/O.
__global__ __launch_bounds__(256) void k_ybuild(
    const unsigned short* __restrict__ sbf,
    const float* __restrict__ psi_v, const int* __restrict__ psi_hi, const int* __restrict__ psi_wi,
    unsigned short* __restrict__ Yt)
{
    __shared__ int   offh[16];
    __shared__ int   wis[16];
    __shared__ float psis[112];

    const int t   = threadIdx.x;
    const int wot = blockIdx.x, ho = blockIdx.y, b = blockIdx.z;

    if (t < 112) psis[t] = psi_v[((t >> 4)*HOUT + ho)*NNZ + (t & 15)];
    if (t < 16){ offh[t] = psi_hi[ho*NNZ + t] * WIN; wis[t] = psi_wi[ho*NNZ + t]; }
    __syncthreads();

    const int wol = t >> 4, cq = t & 15;
    const int wo  = wot*16 + wol;
    const bool valid = (wo < WOUT);
    const int wo_c = valid ? wo : (WOUT - 1);
    const int c0 = cq*8;

    int offs[16];
    #pragma unroll
    for (int n = 0; n < 16; ++n){
        int wv = wis[n] + 2*wo_c;
        wv = (wv >= WIN) ? (wv - WIN) : wv;
        offs[n] = offh[n] + wv;
    }

    const unsigned short* sb = sbf + (size_t)b * HW * 128;

    float ya[8][7];
    #pragma unroll
    for (int ci = 0; ci < 8; ++ci)
        #pragma unroll
        for (int k = 0; k < 7; ++k) ya[ci][k] = 0.f;

    #pragma unroll 4
    for (int n = 0; n < 16; ++n){
        uint4 q = *(const uint4*)(sb + (size_t)offs[n]*128 + c0);
        float g0 = blo(q.x), g1 = bhi(q.x), g2 = blo(q.y), g3 = bhi(q.y);
        float g4 = blo(q.z), g5 = bhi(q.z), g6 = blo(q.w), g7 = bhi(q.w);
        #pragma unroll
        for (int k = 0; k < 7; ++k){
            float pv = psis[k*16 + n];
            ya[0][k] += pv*g0; ya[1][k] += pv*g1; ya[2][k] += pv*g2; ya[3][k] += pv*g3;
            ya[4][k] += pv*g4; ya[5][k] += pv*g5; ya[6][k] += pv*g6; ya[7][k] += pv*g7;
        }
    }
    if (valid){
        unsigned short* yrow = Yt + (size_t)(b*NPB + ho*WOUT + wo) * 896;
        #pragma unroll
        for (int k = 0; k < 7; ++k){
            uint4 pk;
            pk.x = pkbf(ya[0][k], ya[1][k]);
            pk.y = pkbf(ya[2][k], ya[3][k]);
            pk.z = pkbf(ya[4][k], ya[5][k]);
            pk.w = pkbf(ya[6][k], ya[7][k]);
            *(uint4*)(yrow + k*128 + c0) = pk;
        }
    }
}

// ---------------- DISCO GEMM: D[n][co] = Y_t @ W^T, no LDS ----------------
// grid 512 blocks (XCD-swizzled), 256 thr (4 waves, 64n x 64co each).
__global__ __launch_bounds__(256) void k_dgemm(
    const unsigned short* __restrict__ Yt, const unsigned short* __restrict__ wbf,
    const float* __restrict__ bias,
    unsigned short* __restrict__ xdb, float* __restrict__ part)
{
    const int flat = blockIdx.x + 128*(blockIdx.y + 2*blockIdx.z);
    const int rem  = (flat & 7)*64 + (flat >> 3);
    const int coh  = rem & 1;
    const int nt   = (rem >> 1) & 127;
    const int b    = rem >> 8;

    const int t = threadIdx.x;
    const int w = t >> 6, l = t & 63;
    const int lr = l & 15, lk = l >> 4;
    const int wn2 = w >> 1, wc = w & 1;

    const int n0  = nt*128 + wn2*64;
    const int co0 = coh*128 + wc*64;

    const unsigned short* pa[4];
    const unsigned short* pb[4];
    #pragma unroll
    for (int i = 0; i < 4; ++i)
        pa[i] = Yt + (size_t)(b*NPB + n0 + i*16 + lr)*896 + lk*8;
    #pragma unroll
    for (int j = 0; j < 4; ++j)
        pb[j] = wbf + (size_t)(co0 + j*16 + lr)*896 + lk*8;

    f32x4 acc[4][4];
    #pragma unroll
    for (int i = 0; i < 4; ++i)
        #pragma unroll
        for (int j = 0; j < 4; ++j) acc[i][j] = (f32x4)0.f;

    #pragma unroll 2
    for (int ks = 0; ks < 28; ++ks){
        bf16x8 af[4], bf[4];
        #pragma unroll
        for (int i = 0; i < 4; ++i)
            af[i] = __builtin_bit_cast(bf16x8, *(const uint4*)(pa[i] + ks*32));
        #pragma unroll
        for (int j = 0; j < 4; ++j)
            bf[j] = __builtin_bit_cast(bf16x8, *(const uint4*)(pb[j] + ks*32));
        #pragma unroll
        for (int i = 0; i < 4; ++i)
            #pragma unroll
            for (int j = 0; j < 4; ++j)
                acc[i][j] = __builtin_amdgcn_mfma_f32_16x16x32_bf16(af[i], bf[j], acc[i][j], 0, 0, 0);
    }

    float s[2] = {0.f, 0.f}, ss[2] = {0.f, 0.f};
    #pragma unroll
    for (int j = 0; j < 4; ++j){
        const int co = co0 + j*16 + lr;
        const float bv = bias[co];
        unsigned short* outp = xdb + (size_t)(b*256 + co)*NPB;
        const int jp = j >> 1;
        #pragma unroll
        for (int i = 0; i < 4; ++i){
            const int nb = n0 + i*16 + lk*4;
            if (nb < NPB){
                float o0 = acc[i][j][0] + bv, o1 = acc[i][j][1] + bv;
                float o2 = acc[i][j][2] + bv, o3 = acc[i][j][3] + bv;
                uint2 pk; pk.x = pkbf(o0, o1); pk.y = pkbf(o2, o3);
                *(uint2*)(outp + nb) = pk;
                s[jp]  += o0 + o1 + o2 + o3;
                ss[jp] += o0*o0 + o1*o1 + o2*o2 + o3*o3;
            }
        }
    }
    #pragma unroll
    for (int off = 32; off; off >>= 1){
        s[0] += __shfl_down(s[0], off); ss[0] += __shfl_down(ss[0], off);
        s[1] += __shfl_down(s[1], off); ss[1] += __shfl_down(ss[1], off);
    }
    if (l == 0){
        const int bid = (b*2 + coh)*128 + nt;
        part[(bid*8 + w*2 + 0)*2]     = s[0];
        part[(bid*8 + w*2 + 0)*2 + 1] = ss[0];
        part[(bid*8 + w*2 + 1)*2]     = s[1];
        part[(bid*8 + w*2 + 1)*2 + 1] = ss[1];
    }
}

// ---------------- GN2 finalize (split path) ----------------
__global__ __launch_bounds__(256) void k_gn2_final_s(const float* __restrict__ part,
                                                     float* __restrict__ stat){
    const int bg = blockIdx.x, b = bg >> 3, g = bg & 7, t = threadIdx.x;
    const int coh = g >> 2, wc = (g >> 1) & 1, jp = g & 1;
    const int nt = t & 127, wn2 = t >> 7;
    const int bid = (b*2 + coh)*128 + nt;
    const int slot = (wn2*2 + wc)*2 + jp;
    float s  = part[(bid*8 + slot)*2];
    float ss = part[(bid*8 + slot)*2 + 1];
    #pragma unroll
    for (int off = 32; off; off >>= 1){ s += __shfl_down(s, off); ss += __shfl_down(ss, off); }
    __shared__ float ls[4][2];
    if ((t & 63) == 0){ ls[t>>6][0] = s; ls[t>>6][1] = ss; }
    __syncthreads();
    if (t == 0){
        s  = ls[0][0] + ls[1][0] + ls[2][0] + ls[3][0];
        ss = ls[0][1] + ls[1][1] + ls[2][1] + ls[3][1];
        float m = s / (float)N_GN2;
        float v = ss / (float)N_GN2 - m*m;
        stat[bg*2]     = m;
        stat[bg*2 + 1] = 1.0f / sqrtf(v + 1e-5f);
    }
}

// ---------------- GN2 apply + gelu: bf16 in -> fp32 out (split path) ----------------
__global__ __launch_bounds__(256) void k_gn2_apply_s(const unsigned short* __restrict__ xdb,
                                                     float* __restrict__ outd,
                                                     const float* __restrict__ stat,
                                                     const float* __restrict__ g2a,
                                                     const float* __restrict__ be2){
    const int gid = blockIdx.x*256 + threadIdx.x;
    const int stride = gridDim.x*256;
    for (int v = gid; v < 2096640; v += stride){
        uint2 q = ((const uint2*)xdb)[v];
        int i  = v << 2;
        int bc = i / 16380;
        int co = bc & 255, b = bc >> 8;
        float m  = stat[(b*8 + (co >> 5))*2];
        float r  = stat[(b*8 + (co >> 5))*2 + 1];
        float a  = r * g2a[co];
        float bb = be2[co] - m*a;
        float4 o;
        o.x = gelu_f(__builtin_fmaf(blo(q.x), a, bb));
        o.y = gelu_f(__builtin_fmaf(bhi(q.x), a, bb));
        o.z = gelu_f(__builtin_fmaf(blo(q.y), a, bb));
        o.w = gelu_f(__builtin_fmaf(bhi(q.y), a, bb));
        ((float4*)outd)[v] = o;
    }
}

// ================= FALLBACK (fused disco, fp32 in-place apply) =================
__global__ __launch_bounds__(256, 2) void k_disco_fb(
    const float* __restrict__ skip,
    const float* __restrict__ psi_v, const int* __restrict__ psi_hi, const int* __restrict__ psi_wi,
    const unsigned short* __restrict__ wbf, const float* __restrict__ bias,
    float* __restrict__ xdown, float* __restrict__ part)
{
    __shared__ unsigned short yT[96*256];

    const int t   = threadIdx.x;
    const int woh = blockIdx.x;
    const int ho  = blockIdx.y;
    const int z   = blockIdx.z;
    const int b   = z >> 1, coh = z & 1;
    const int co0 = coh * 128;
    const int wo0 = woh * 90;

    const int w  = t >> 6;
    const int l  = t & 63;
    const int wm = w >> 1, wn = w & 1;

    const int wol = t & 31;
    const int cq  = t >> 5;
    const unsigned sw = (unsigned)(wol & 7) << 4;

    const float* skipb = skip + (size_t)b * (128*HW);

    f32x4 acc[4][3];
    #pragma unroll
    for (int m = 0; m < 4; ++m)
        #pragma unroll
        for (int nf = 0; nf < 3; ++nf) acc[m][nf] = (f32x4)0.f;

    #pragma unroll 1
    for (int cc = 0; cc < 4; ++cc){
        __syncthreads();
        const float* bp0 = skipb + (size_t)(cc*32 + cq*4 + 0)*HW;
        const float* bp1 = skipb + (size_t)(cc*32 + cq*4 + 1)*HW;
        const float* bp2 = skipb + (size_t)(cc*32 + cq*4 + 2)*HW;
        const float* bp3 = skipb + (size_t)(cc*32 + cq*4 + 3)*HW;

        float ya[3][4][7];
        #pragma unroll
        for (int wj = 0; wj < 3; ++wj)
            #pragma unroll
            for (int ci = 0; ci < 4; ++ci)
                #pragma unroll
                for (int k = 0; k < 7; ++k) ya[wj][ci][k] = 0.f;

        #pragma unroll 2
        for (int n = 0; n < NNZ; ++n){
            const int hi = psi_hi[ho*NNZ + n];
            const int wi = psi_wi[ho*NNZ + n];
            float ps[7];
            #pragma unroll
            for (int k = 0; k < 7; ++k) ps[k] = psi_v[(k*HOUT + ho)*NNZ + n];
            const int rowb = hi * WIN;
            #pragma unroll
            for (int wj = 0; wj < 3; ++wj){
                int wv = wi + 2*(wo0 + wol + 32*wj);
                wv = (wv >= 720) ? (wv - 720) : (wv >= 360 ? (wv - 360) : wv);
                const int off = rowb + wv;
                float g0 = bp0[off], g1 = bp1[off], g2 = bp2[off], g3 = bp3[off];
                #pragma unroll
                for (int k = 0; k < 7; ++k){
                    float pv = ps[k];
                    ya[wj][0][k] += pv*g0; ya[wj][1][k] += pv*g1;
                    ya[wj][2][k] += pv*g2; ya[wj][3][k] += pv*g3;
                }
            }
        }
        #pragma unroll
        for (int wj = 0; wj < 3; ++wj){
            char* row = (char*)yT + (wol + 32*wj)*512;
            #pragma unroll
            for (int k = 0; k < 7; ++k){
                unsigned base = ((unsigned)(k*64 + cq*8)) ^ sw;
                *(unsigned*)(row + base)     = pkbf(ya[wj][0][k], ya[wj][1][k]);
                *(unsigned*)(row + base + 4) = pkbf(ya[wj][2][k], ya[wj][3][k]);
            }
        }
        __syncthreads();

        const unsigned short* wrow = wbf + (size_t)(co0 + wm*64 + (l & 15))*896
                                         + cc*32 + ((l >> 4) << 3);
        #pragma unroll
        for (int k = 0; k < 7; ++k){
            bf16x8 af[4];
            #pragma unroll
            for (int m = 0; m < 4; ++m)
                af[m] = __builtin_bit_cast(bf16x8,
                          *(const uint4*)(wrow + (size_t)m*16*896 + k*128));
            bf16x8 bfv[3];
            #pragma unroll
            for (int nf = 0; nf < 3; ++nf){
                const int wo_l = wn*48 + nf*16 + (l & 15);
                unsigned off = (unsigned)(wo_l*512)
                             + (((unsigned)(k*64) + ((unsigned)(l >> 4) << 4))
                                ^ ((unsigned)(wo_l & 7) << 4));
                bfv[nf] = __builtin_bit_cast(bf16x8, *(const uint4*)((const char*)yT + off));
            }
            #pragma unroll
            for (int m = 0; m < 4; ++m)
                #pragma unroll
                for (int nf = 0; nf < 3; ++nf)
                    acc[m][nf] = __builtin_amdgcn_mfma_f32_16x16x32_bf16(af[m], bfv[nf], acc[m][nf], 0, 0, 0);
        }
    }

    float s[2] = {0.f, 0.f}, ss[2] = {0.f, 0.f};
    #pragma unroll
    for (int m = 0; m < 4; ++m){
        const int pair = m >> 1;
        const int cob = co0 + wm*64 + m*16 + ((l >> 4) << 2);
        float4 bv = *(const float4*)(bias + cob);
        #pragma unroll
        for (int nf = 0; nf < 3; ++nf){
            const int wo_t = wn*48 + nf*16 + (l & 15);
            if (wo_t < 90){
                #pragma unroll
                for (int r = 0; r < 4; ++r){
                    float v = acc[m][nf][r] + ((const float*)&bv)[r];
                    xdown[((size_t)(b*256 + cob + r)*HOUT + ho)*WOUT + wo0 + wo_t] = v;
                    s[pair] += v; ss[pair] += v*v;
                }
            }
        }
    }
    #pragma unroll
    for (int off = 32; off; off >>= 1){
        s[0] += __shfl_down(s[0], off); ss[0] += __shfl_down(ss[0], off);
        s[1] += __shfl_down(s[1], off); ss[1] += __shfl_down(ss[1], off);
    }
    if (l == 0){
        const int tid = (z*91 + ho)*2 + woh;
        part[(tid*8 + w*2 + 0)*2]     = s[0];
        part[(tid*8 + w*2 + 0)*2 + 1] = ss[0];
        part[(tid*8 + w*2 + 1)*2]     = s[1];
        part[(tid*8 + w*2 + 1)*2 + 1] = ss[1];
    }
}

__global__ __launch_bounds__(256) void k_gn2_final_fb(const float* __restrict__ part,
                                                      float* __restrict__ stat){
    const int bg = blockIdx.x, b = bg >> 3, g = bg & 7, t = threadIdx.x;
    const int coh = g >> 2, gl = g & 3, wm = gl >> 1, pair = gl & 1;
    float s = 0.f, ss = 0.f;
    for (int i = t; i < 364; i += 256){
        int ho = i >> 2, r = i & 3, woh = r >> 1, wn = r & 1;
        int tid = (((b*2 + coh)*91 + ho)*2 + woh);
        int slot = (wm*2 + wn)*2 + pair;
        s  += part[(tid*8 + slot)*2];
        ss += part[(tid*8 + slot)*2 + 1];
    }
    #pragma unroll
    for (int off = 32; off; off >>= 1){ s += __shfl_down(s, off); ss += __shfl_down(ss, off); }
    __shared__ float ls[4][2];
    if ((t & 63) == 0){ ls[t>>6][0] = s; ls[t>>6][1] = ss; }
    __syncthreads();
    if (t == 0){
        s  = ls[0][0] + ls[1][0] + ls[2][0] + ls[3][0];
        ss = ls[0][1] + ls[1][1] + ls[2][1] + ls[3][1];
        float m = s / (float)N_GN2;
        float v = ss / (float)N_GN2 - m*m;
        stat[bg*2]     = m;
        stat[bg*2 + 1] = 1.0f / sqrtf(v + 1e-5f);
    }
}

__global__ __launch_bounds__(256) void k_gn2_apply(float* __restrict__ xd,
                                                   const float* __restrict__ stat,
                                                   const float* __restrict__ g2a,
                                                   const float* __restrict__ be2){
    const int gid = blockIdx.x*256 + threadIdx.x;
    const int stride = gridDim.x*256;
    for (int v = gid; v < 2096640; v += stride){
        float4 q = ((float4*)xd)[v];
        int i  = v << 2;
        int bc = i / 16380;
        int co = bc & 255, b = bc >> 8;
        float m  = stat[(b*8 + (co >> 5))*2];
        float r  = stat[(b*8 + (co >> 5))*2 + 1];
        float a  = r * g2a[co];
        float bb = be2[co] - m*a;
        q.x = gelu_f(__builtin_fmaf(q.x, a, bb));
        q.y = gelu_f(__builtin_fmaf(q.y, a, bb));
        q.z = gelu_f(__builtin_fmaf(q.z, a, bb));
        q.w = gelu_f(__builtin_fmaf(q.w, a, bb));
        ((float4*)xd)[v] = q;
    }
}

extern "C" void kernel_launch(void* const* d_in, const int* in_sizes, int n_in,
                              void* d_out, int out_size, void* d_ws, size_t ws_size,
                              hipStream_t stream){
    const float* x      = (const float*)d_in[0];
    const float* psi_v  = (const float*)d_in[1];
    const int*   psi_hi = (const int*)d_in[2];
    const int*   psi_wi = (const int*)d_in[3];
    const float* weight = (const float*)d_in[4];
    const float* bias   = (const float*)d_in[5];
    const float* g1     = (const float*)d_in[6];
    const float* be1    = (const float*)d_in[7];
    const float* w1     = (const float*)d_in[8];
    const float* b1     = (const float*)d_in[9];
    const float* w2     = (const float*)d_in[10];
    const float* b2     = (const float*)d_in[11];
    const float* g2     = (const float*)d_in[12];
    const float* be2    = (const float*)d_in[13];

    float* skip  = (float*)d_out;
    float* xdown = skip + 16680960;          // 2*128*181*360

    float* ws       = (float*)d_ws;
    float* gn1_part = ws;                                   // 4096 f
    float* gn1_stat = ws + 4096;                            // 32 f (unused, kept for layout)
    float* gn2_part = ws + 4128;                            // 11648 f
    float* gn2_stat = ws + 15776;                           // 32 f
    unsigned short* wbf = (unsigned short*)(ws + 15808);    // 229376 us -> 130496
    unsigned short* w1f = (unsigned short*)(ws + 130496);   // 65536 us  -> 163264
    float*          b1f = ws + 163264;                      // 512 f     -> 163776
    unsigned short* w2b = (unsigned short*)(ws + 163776);   // 32768 us  -> 180160
    unsigned short* sbf = (unsigned short*)(ws + 180160);   // 16,680,960 us -> 8,520,640
    unsigned short* xdb = sbf;                              // overlay
    unsigned short* Yt  = (unsigned short*)(ws + 8520640);  // 29,352,960 us -> 23,197,120
    const size_t need = 23197120ull * 4ull;                 // ~92.79 MB

    const bool split = (ws_size >= need);
    (void)gn1_stat;

    k_prep       <<<2432, 256, 0, stream>>>(x, gn1_part, weight, wbf, w2, w2b);
    k_fold       <<<512, 64, 0, stream>>>(gn1_part, w1, b1, g1, be1, w1f, b1f);
    k_mlp        <<<dim3(1019, 2), 256, 0, stream>>>(x, w1f, b1f, w2b, b2,
                                                     skip, split ? sbf : (unsigned short*)nullptr);
    if (split){
        k_ybuild   <<<dim3(12, 91, 2), 256, 0, stream>>>(sbf, psi_v, psi_hi, psi_wi, Yt);
        k_dgemm    <<<dim3(128, 2, 2), 256, 0, stream>>>(Yt, wbf, bias, xdb, gn2_part);
        k_gn2_final_s<<<16, 256, 0, stream>>>(gn2_part, gn2_stat);
        k_gn2_apply_s<<<2048, 256, 0, stream>>>(xdb, xdown, gn2_stat, g2, be2);
    } else {
        k_disco_fb <<<dim3(2, 91, 4), 256, 0, stream>>>(skip, psi_v, psi_hi, psi_wi,
                                                        wbf, bias, xdown, gn2_part);
        k_gn2_final_fb<<<16, 256, 0, stream>>>(gn2_part, gn2_stat);
        k_gn2_apply<<<2048, 256, 0, stream>>>(xdown, gn2_stat, g2, be2);
    }
}

// Round 15
// 148.810 us; speedup vs baseline: 1.5231x; 1.1908x over previous
//
#include <hip/hip_runtime.h>

// DiscoDownBlock: GN1 -> 1x1 MLP (expand/gelu/project) + residual -> DISCO S2 conv
//                 -> GN2 -> gelu.  Outputs: skip [2,128,181,360], x_down [2,256,91,180]
//
// Round 15 (on R14 base, 177us):
//  - k_dfuse fuses ybuild + dgemm: Y K-chunks built in XOR-swizzled LDS
//    (512B rows, disco_fb-proven layout), MFMA consumes from LDS; kills the
//    118MB Yt HBM round-trip + one launch. 64-row n-tiles span <=2 ho (psi x2
//    staged in LDS). Also fixes dgemm's Yt tail over-read.
//  - k_gn2_apply_s absorbs gn2_final (per-block L2-hot reduce of 8192 partials).
//  - k_prep / k_fold / k_mlp byte-identical to R14.

#define HW      65160      // 181*360
#define HIN     181
#define WIN     360
#define HOUT    91
#define WOUT    180
#define CIN     128
#define COUT    256
#define KB      7
#define NNZ     16
#define N_GN1   1042560    // 16*HW
#define N_GN2   524160     // 32*91*180
#define NPB     16380      // 91*180 (per-batch n)

typedef float  f32x4  __attribute__((ext_vector_type(4)));
typedef __bf16 bf16x8 __attribute__((ext_vector_type(8)));

__device__ __forceinline__ unsigned short f2b(float v){
    return __builtin_bit_cast(unsigned short, (__bf16)v);
}
__device__ __forceinline__ unsigned pkbf(float a, float b){
    return (unsigned)__builtin_bit_cast(unsigned short, (__bf16)a)
         | ((unsigned)__builtin_bit_cast(unsigned short, (__bf16)b) << 16);
}
__device__ __forceinline__ float blo(unsigned u){ return __uint_as_float(u << 16); }
__device__ __forceinline__ float bhi(unsigned u){ return __uint_as_float(u & 0xffff0000u); }

// gelu via sigmoid identity: 0.5v(1+tanh z) = v * sigma(2z).
__device__ __forceinline__ float gelu_f(float v){
    float z = v * __builtin_fmaf(0.0356774081363f, v*v, 0.7978845608028654f);
    float e = __builtin_amdgcn_exp2f(-2.8853900817779268f * z);
    return v * __builtin_amdgcn_rcpf(1.0f + e);
}

// ---------------- prep: GN1 partials + weight converts (merged) ----------------
__global__ __launch_bounds__(256) void k_prep(
    const float* __restrict__ x, float* __restrict__ part,
    const float* __restrict__ wsrc, unsigned short* __restrict__ wbf,
    const float* __restrict__ w2, unsigned short* __restrict__ w2b)
{
    const int blk_id = blockIdx.x;
    const int t = threadIdx.x;

    if (blk_id < 2048){
        const int bg = blk_id >> 7, blk = blk_id & 127;
        const float4* p4 = (const float4*)(x + (size_t)bg * N_GN1);
        float s = 0.f, ss = 0.f;
        for (int v = blk*256 + t; v < N_GN1/4; v += 128*256){
            float4 q = p4[v];
            s  += q.x + q.y + q.z + q.w;
            ss += q.x*q.x + q.y*q.y + q.z*q.z + q.w*q.w;
        }
        #pragma unroll
        for (int off = 32; off; off >>= 1){ s += __shfl_down(s, off); ss += __shfl_down(ss, off); }
        __shared__ float ls[4][2];
        if ((t & 63) == 0){ ls[t>>6][0] = s; ls[t>>6][1] = ss; }
        __syncthreads();
        if (t == 0){
            s  = ls[0][0] + ls[1][0] + ls[2][0] + ls[3][0];
            ss = ls[0][1] + ls[1][1] + ls[2][1] + ls[3][1];
            part[(bg*128 + blk)*2]     = s;
            part[(bg*128 + blk)*2 + 1] = ss;
        }
    } else if (blk_id < 2304){
        const int co = blk_id - 2048;
        for (int r = t; r < 896; r += 256){
            int k = r >> 7, c = r & 127;
            wbf[co*896 + r] = f2b(wsrc[co*896 + c*7 + k]);
        }
    } else {
        const int i = (blk_id - 2304)*256 + t;
        if (i < 32768) w2b[i] = f2b(w2[i]);
    }
}

// ---------------- fold: GN1 finalize (redundant per block) + w1 fold ----------------
__global__ __launch_bounds__(64) void k_fold(
    const float* __restrict__ part,
    const float* __restrict__ w1, const float* __restrict__ b1,
    const float* __restrict__ g1, const float* __restrict__ be1,
    unsigned short* __restrict__ w1f, float* __restrict__ b1f)
{
    const int id = blockIdx.x;         // b*256 + oc
    const int b = id >> 8, oc = id & 255;
    const int l = threadIdx.x;

    float mArr[8], rArr[8];
    #pragma unroll
    for (int g = 0; g < 8; ++g){
        const int bg = b*8 + g;
        float s  = part[(bg*128 + l)*2]     + part[(bg*128 + 64 + l)*2];
        float ss = part[(bg*128 + l)*2 + 1] + part[(bg*128 + 64 + l)*2 + 1];
        #pragma unroll
        for (int off = 32; off; off >>= 1){ s += __shfl_down(s, off); ss += __shfl_down(ss, off); }
        s = __shfl(s, 0); ss = __shfl(ss, 0);
        float m = s / (float)N_GN1;
        float v = ss / (float)N_GN1 - m*m;
        mArr[g] = m;
        rArr[g] = 1.0f / sqrtf(v + 1e-5f);
    }

    float acc = 0.f;
    #pragma unroll
    for (int j = 0; j < 2; ++j){
        const int c = l + j*64;
        const int g = c >> 4;
        float a  = rArr[g] * g1[c];
        float bb = be1[c] - mArr[g]*a;
        float wv = w1[oc*128 + c];
        w1f[((size_t)b*256 + oc)*128 + c] = f2b(wv * a);
        acc += wv * bb;
    }
    #pragma unroll
    for (int off = 32; off; off >>= 1) acc += __shfl_down(acc, off);
    if (l == 0) b1f[b*256 + oc] = b1[oc] + acc;
}

// ---------------- fused MLP + residual (MFMA, 2-half pipeline) ----------------
__global__ __launch_bounds__(256, 4) void k_mlp(
    const float* __restrict__ x,
    const unsigned short* __restrict__ w1f, const float* __restrict__ b1f,
    const unsigned short* __restrict__ w2b, const float* __restrict__ b2,
    float* __restrict__ skip, unsigned short* __restrict__ sbf)
{
    __shared__ unsigned short xns[64*128];
    __shared__ unsigned short h1h[64*128];

    const int t = threadIdx.x;
    const int b = blockIdx.y;
    const int pix0 = blockIdx.x * 64;
    const int valid = min(64, HW - pix0);

    const int w  = t >> 6, l = t & 63;
    const int lr = l & 15, lk = l >> 4;

    {
        const int p = l;
        const unsigned sw = ((unsigned)(p & 7)) << 4;
        const float* xb = x + (size_t)b*128*HW + pix0 + p;
        #pragma unroll
        for (int i = 0; i < 8; ++i){
            const int c0 = w*32 + i*4;
            uint2 pk;
            if (p < valid){
                pk.x = pkbf(xb[(size_t)(c0+0)*HW], xb[(size_t)(c0+1)*HW]);
                pk.y = pkbf(xb[(size_t)(c0+2)*HW], xb[(size_t)(c0+3)*HW]);
            } else { pk.x = 0u; pk.y = 0u; }
            *(uint2*)((char*)xns + p*256 + (((unsigned)(c0*2)) ^ sw)) = pk;
        }
    }
    __syncthreads();

    f32x4 acc2[4][2];
    {
        const float bv0 = b2[w*32 + lr];
        const float bv1 = b2[w*32 + 16 + lr];
        #pragma unroll
        for (int pm = 0; pm < 4; ++pm){
            acc2[pm][0] = (f32x4)bv0;
            acc2[pm][1] = (f32x4)bv1;
        }
    }

    const unsigned short* w1p = w1f + (size_t)b*256*128;

    #pragma unroll
    for (int half = 0; half < 2; ++half){
        {
            f32x4 acc1[2][4];
            #pragma unroll
            for (int m = 0; m < 2; ++m){
                float4 bv = *(const float4*)(b1f + b*256 + half*128 + w*32 + m*16 + lk*4);
                #pragma unroll
                for (int nf = 0; nf < 4; ++nf) acc1[m][nf] = __builtin_bit_cast(f32x4, bv);
            }
            const unsigned short* wr = w1p + (size_t)(half*128 + w*32 + lr)*128 + lk*8;
            #pragma unroll
            for (int ks = 0; ks < 4; ++ks){
                bf16x8 af[2];
                #pragma unroll
                for (int m = 0; m < 2; ++m)
                    af[m] = __builtin_bit_cast(bf16x8, *(const uint4*)(wr + m*16*128 + ks*32));
                bf16x8 bfv[4];
                #pragma unroll
                for (int nf = 0; nf < 4; ++nf){
                    const int p = nf*16 + lr;
                    unsigned off = (unsigned)(p*256)
                                 + (((unsigned)(ks*64 + lk*16)) ^ (((unsigned)(p & 7)) << 4));
                    bfv[nf] = __builtin_bit_cast(bf16x8, *(const uint4*)((const char*)xns + off));
                }
                #pragma unroll
                for (int m = 0; m < 2; ++m)
                    #pragma unroll
                    for (int nf = 0; nf < 4; ++nf)
                        acc1[m][nf] = __builtin_amdgcn_mfma_f32_16x16x32_bf16(af[m], bfv[nf], acc1[m][nf], 0, 0, 0);
            }
            #pragma unroll
            for (int m = 0; m < 2; ++m){
                const int oc0 = w*32 + m*16 + lk*4;
                #pragma unroll
                for (int nf = 0; nf < 4; ++nf){
                    const int p = nf*16 + lr;
                    uint2 pk;
                    pk.x = pkbf(gelu_f(acc1[m][nf][0]), gelu_f(acc1[m][nf][1]));
                    pk.y = pkbf(gelu_f(acc1[m][nf][2]), gelu_f(acc1[m][nf][3]));
                    unsigned off = (unsigned)(p*256)
                                 + (((unsigned)(oc0*2)) ^ (((unsigned)(p & 7)) << 4));
                    *(uint2*)((char*)h1h + off) = pk;
                }
            }
        }
        __syncthreads();

        {
            const unsigned short* wr = w2b + (size_t)(w*32 + lr)*256 + half*128 + lk*8;
            #pragma unroll
            for (int ks = 0; ks < 4; ++ks){
                bf16x8 bfw[2];
                #pragma unroll
                for (int cn = 0; cn < 2; ++cn)
                    bfw[cn] = __builtin_bit_cast(bf16x8, *(const uint4*)(wr + cn*16*256 + ks*32));
                bf16x8 afh[4];
                #pragma unroll
                for (int pm = 0; pm < 4; ++pm){
                    const int p = pm*16 + lr;
                    unsigned off = (unsigned)(p*256)
                                 + (((unsigned)(ks*64 + lk*16)) ^ (((unsigned)(p & 7)) << 4));
                    afh[pm] = __builtin_bit_cast(bf16x8, *(const uint4*)((const char*)h1h + off));
                }
                #pragma unroll
                for (int pm = 0; pm < 4; ++pm)
                    #pragma unroll
                    for (int cn = 0; cn < 2; ++cn)
                        acc2[pm][cn] = __builtin_amdgcn_mfma_f32_16x16x32_bf16(afh[pm], bfw[cn], acc2[pm][cn], 0, 0, 0);
            }
        }
        if (half == 0) __syncthreads();
    }

    #pragma unroll
    for (int pm = 0; pm < 4; ++pm){
        const int p0 = pm*16 + lk*4;
        if (p0 < valid){
            #pragma unroll
            for (int cn = 0; cn < 2; ++cn){
                const int c = w*32 + cn*16 + lr;
                size_t base = (size_t)(b*128 + c)*HW + pix0 + p0;
                float4 o;
                #pragma unroll
                for (int r = 0; r < 4; ++r){
                    const int p = p0 + r;
                    unsigned off = (unsigned)(p*256)
                                 + (((unsigned)(c*2)) ^ (((unsigned)(p & 7)) << 4));
                    unsigned short us = *(const unsigned short*)((const char*)xns + off);
                    ((float*)&o)[r] = acc2[pm][cn][r] + blo((unsigned)us);
                }
                *(float4*)(skip + base) = o;
                if (sbf){
                    unsigned short* sp = sbf + ((size_t)b*HW + pix0 + p0)*128 + c;
                    sp[0]   = f2b(o.x);
                    sp[128] = f2b(o.y);
                    sp[256] = f2b(o.z);
                    sp[384] = f2b(o.w);
                }
            }
        }
    }
}

// ---------------- fused DISCO: gather+psi -> swizzled LDS Y -> MFMA ----------------
// grid 512 (XCD-swizzled (nt 256, b 2)), 256 thr (4 waves; wave w = co w*64..+64).
// LDS Y tile: [64 n][512B row], K-chunk cc: byte (k*64 + cl*2) ^ ((n&7)<<4).
__global__ __launch_bounds__(256) void k_dfuse(
    const unsigned short* __restrict__ sbf,
    const float* __restrict__ psi_v, const int* __restrict__ psi_hi, const int* __restrict__ psi_wi,
    const unsigned short* __restrict__ wbf, const float* __restrict__ bias,
    unsigned short* __restrict__ xdb, float* __restrict__ part)
{
    __shared__ unsigned short yT[64*256];   // 32 KB
    __shared__ float psis[2][112];
    __shared__ int   his[2][16], wis[2][16];

    const int flat = blockIdx.x + 256*blockIdx.y;
    const int rem  = (flat & 7)*64 + (flat >> 3);      // XCD-contiguous (512 = 8*64)
    const int nt   = rem & 255;
    const int b    = rem >> 8;
    const int n0   = nt*64;

    const int t = threadIdx.x;
    const int w = t >> 6, l = t & 63;
    const int lr = l & 15, lk = l >> 4;

    const int ho0 = n0 / WOUT;
    const int ho1 = min((n0 + 63) / WOUT, HOUT - 1);

    if (t < 112)        psis[0][t]       = psi_v[((t >> 4)*HOUT + ho0)*NNZ + (t & 15)];
    else if (t < 224)   psis[1][t - 112] = psi_v[(((t - 112) >> 4)*HOUT + ho1)*NNZ + ((t - 112) & 15)];
    else if (t < 240){  his[0][t - 224] = psi_hi[ho0*NNZ + t - 224];
                        wis[0][t - 224] = psi_wi[ho0*NNZ + t - 224]; }
    else             {  his[1][t - 240] = psi_hi[ho1*NNZ + t - 240];
                        wis[1][t - 240] = psi_wi[ho1*NNZ + t - 240]; }
    __syncthreads();

    // build mapping: thread (row = t>>2, cq = t&3 -> 8 channels)
    const int row = t >> 2, cq = t & 3;
    const int n_c = min(n0 + row, NPB - 1);
    const int ho  = n_c / WOUT;
    const int wo  = n_c - ho*WOUT;
    const int sel = (ho == ho0) ? 0 : 1;
    const unsigned swr = ((unsigned)(row & 7)) << 4;

    int offs[16];
    #pragma unroll
    for (int n = 0; n < 16; ++n){
        int wv = wis[sel][n] + 2*wo;
        wv = (wv >= WIN) ? (wv - WIN) : wv;
        offs[n] = his[sel][n]*WIN + wv;
    }
    const unsigned short* sb = sbf + (size_t)b * HW * 128;

    f32x4 acc[4][4];
    #pragma unroll
    for (int i = 0; i < 4; ++i)
        #pragma unroll
        for (int j = 0; j < 4; ++j) acc[i][j] = (f32x4)0.f;

    #pragma unroll 1
    for (int cc = 0; cc < 4; ++cc){
        __syncthreads();                    // previous MFMA reads done
        // ---- build Y chunk: channels cc*32 + cq*8 .. +8 ----
        {
            const int cl0 = cq*8;
            float ya[8][7];
            #pragma unroll
            for (int ci = 0; ci < 8; ++ci)
                #pragma unroll
                for (int k = 0; k < 7; ++k) ya[ci][k] = 0.f;

            #pragma unroll 4
            for (int n = 0; n < 16; ++n){
                uint4 q = *(const uint4*)(sb + (size_t)offs[n]*128 + cc*32 + cl0);
                float g0 = blo(q.x), g1 = bhi(q.x), g2 = blo(q.y), g3 = bhi(q.y);
                float g4 = blo(q.z), g5 = bhi(q.z), g6 = blo(q.w), g7 = bhi(q.w);
                #pragma unroll
                for (int k = 0; k < 7; ++k){
                    float pv = psis[sel][k*16 + n];
                    ya[0][k] += pv*g0; ya[1][k] += pv*g1; ya[2][k] += pv*g2; ya[3][k] += pv*g3;
                    ya[4][k] += pv*g4; ya[5][k] += pv*g5; ya[6][k] += pv*g6; ya[7][k] += pv*g7;
                }
            }
            char* rowp = (char*)yT + row*512;
            #pragma unroll
            for (int k = 0; k < 7; ++k){
                uint4 pk;
                pk.x = pkbf(ya[0][k], ya[1][k]);
                pk.y = pkbf(ya[2][k], ya[3][k]);
                pk.z = pkbf(ya[4][k], ya[5][k]);
                pk.w = pkbf(ya[6][k], ya[7][k]);
                *(uint4*)(rowp + (((unsigned)(k*64 + cl0*2)) ^ swr)) = pk;
            }
        }
        __syncthreads();

        // ---- MFMA: 7 K-slices (k, 32 c) ----
        const unsigned short* wr = wbf + (size_t)(w*64 + lr)*896 + cc*32 + lk*8;
        #pragma unroll
        for (int k = 0; k < 7; ++k){
            bf16x8 af[4];
            #pragma unroll
            for (int i = 0; i < 4; ++i){
                const int r = i*16 + lr;
                unsigned off = (unsigned)(r*512)
                             + (((unsigned)(k*64 + lk*16)) ^ (((unsigned)(r & 7)) << 4));
                af[i] = __builtin_bit_cast(bf16x8, *(const uint4*)((const char*)yT + off));
            }
            bf16x8 bfw[4];
            #pragma unroll
            for (int j = 0; j < 4; ++j)
                bfw[j] = __builtin_bit_cast(bf16x8, *(const uint4*)(wr + (size_t)j*16*896 + k*128));
            #pragma unroll
            for (int i = 0; i < 4; ++i)
                #pragma unroll
                for (int j = 0; j < 4; ++j)
                    acc[i][j] = __builtin_amdgcn_mfma_f32_16x16x32_bf16(af[i], bfw[j], acc[i][j], 0, 0, 0);
        }
    }

    // ---- epilogue: bias, bf16 store (n-masked), GN2 partials ----
    float s[2] = {0.f, 0.f}, ss[2] = {0.f, 0.f};
    #pragma unroll
    for (int j = 0; j < 4; ++j){
        const int co = w*64 + j*16 + lr;
        const float bv = bias[co];
        unsigned short* outp = xdb + (size_t)(b*256 + co)*NPB;
        const int jp = j >> 1;
        #pragma unroll
        for (int i = 0; i < 4; ++i){
            const int nb = n0 + i*16 + lk*4;
            if (nb < NPB){
                float o0 = acc[i][j][0] + bv, o1 = acc[i][j][1] + bv;
                float o2 = acc[i][j][2] + bv, o3 = acc[i][j][3] + bv;
                uint2 pk; pk.x = pkbf(o0, o1); pk.y = pkbf(o2, o3);
                *(uint2*)(outp + nb) = pk;
                s[jp]  += o0 + o1 + o2 + o3;
                ss[jp] += o0*o0 + o1*o1 + o2*o2 + o3*o3;
            }
        }
    }
    #pragma unroll
    for (int off = 32; off; off >>= 1){
        s[0] += __shfl_down(s[0], off); ss[0] += __shfl_down(ss[0], off);
        s[1] += __shfl_down(s[1], off); ss[1] += __shfl_down(ss[1], off);
    }
    if (l == 0){
        const int bid = b*256 + nt;
        const int g0 = w*2;                 // group = co/32 = w*2 + jp
        part[(bid*8 + g0 + 0)*2]     = s[0];
        part[(bid*8 + g0 + 0)*2 + 1] = ss[0];
        part[(bid*8 + g0 + 1)*2]     = s[1];
        part[(bid*8 + g0 + 1)*2 + 1] = ss[1];
    }
}

// ---------------- GN2 finalize + apply + gelu (merged, split path) ----------------
// grid 512 x 256. Preamble: redundant per-block reduce of part[512*8*2] (L2-hot).
__global__ __launch_bounds__(256) void k_gn2_apply_s(const unsigned short* __restrict__ xdb,
                                                     float* __restrict__ outd,
                                                     const float* __restrict__ part,
                                                     const float* __restrict__ g2a,
                                                     const float* __restrict__ be2){
    __shared__ float ls[16][2];             // [b*8+g][{m, rinv}]
    const int t = threadIdx.x;
    {
        const int grp = t >> 4;             // 0..15 = b*8 + g
        const int bb = grp >> 3, g = grp & 7;
        const int l16 = t & 15;
        float s = 0.f, ssum = 0.f;
        #pragma unroll
        for (int j = 0; j < 16; ++j){
            const int nt = l16 + j*16;
            const int idx = ((bb*256 + nt)*8 + g)*2;
            s    += part[idx];
            ssum += part[idx + 1];
        }
        #pragma unroll
        for (int off = 8; off; off >>= 1){
            s    += __shfl_xor(s, off);
            ssum += __shfl_xor(ssum, off);
        }
        if (l16 == 0){
            float m = s / (float)N_GN2;
            float v = ssum / (float)N_GN2 - m*m;
            ls[grp][0] = m;
            ls[grp][1] = 1.0f / sqrtf(v + 1e-5f);
        }
    }
    __syncthreads();

    const int gid = blockIdx.x*256 + t;
    const int stride = gridDim.x*256;
    for (int v = gid; v < 2096640; v += stride){
        uint2 q = ((const uint2*)xdb)[v];
        int i  = v << 2;
        int bc = i / 16380;
        int co = bc & 255, b = bc >> 8;
        const int grp = b*8 + (co >> 5);
        float m  = ls[grp][0];
        float r  = ls[grp][1];
        float a  = r * g2a[co];
        float bb = be2[co] - m*a;
        float4 o;
        o.x = gelu_f(__builtin_fmaf(blo(q.x), a, bb));
        o.y = gelu_f(__builtin_fmaf(bhi(q.x), a, bb));
        o.z = gelu_f(__builtin_fmaf(blo(q.y), a, bb));
        o.w = gelu_f(__builtin_fmaf(bhi(q.y), a, bb));
        ((float4*)outd)[v] = o;
    }
}

// ================= FALLBACK (fused disco, fp32 in-place apply) =================
__global__ __launch_bounds__(256, 2) void k_disco_fb(
    const float* __restrict__ skip,
    const float* __restrict__ psi_v, const int* __restrict__ psi_hi, const int* __restrict__ psi_wi,
    const unsigned short* __restrict__ wbf, const float* __restrict__ bias,
    float* __restrict__ xdown, float* __restrict__ part)
{
    __shared__ unsigned short yT[96*256];

    const int t   = threadIdx.x;
    const int woh = blockIdx.x;
    const int ho  = blockIdx.y;
    const int z   = blockIdx.z;
    const int b   = z >> 1, coh = z & 1;
    const int co0 = coh * 128;
    const int wo0 = woh * 90;

    const int w  = t >> 6;
    const int l  = t & 63;
    const int wm = w >> 1, wn = w & 1;

    const int wol = t & 31;
    const int cq  = t >> 5;
    const unsigned sw = (unsigned)(wol & 7) << 4;

    const float* skipb = skip + (size_t)b * (128*HW);

    f32x4 acc[4][3];
    #pragma unroll
    for (int m = 0; m < 4; ++m)
        #pragma unroll
        for (int nf = 0; nf < 3; ++nf) acc[m][nf] = (f32x4)0.f;

    #pragma unroll 1
    for (int cc = 0; cc < 4; ++cc){
        __syncthreads();
        const float* bp0 = skipb + (size_t)(cc*32 + cq*4 + 0)*HW;
        const float* bp1 = skipb + (size_t)(cc*32 + cq*4 + 1)*HW;
        const float* bp2 = skipb + (size_t)(cc*32 + cq*4 + 2)*HW;
        const float* bp3 = skipb + (size_t)(cc*32 + cq*4 + 3)*HW;

        float ya[3][4][7];
        #pragma unroll
        for (int wj = 0; wj < 3; ++wj)
            #pragma unroll
            for (int ci = 0; ci < 4; ++ci)
                #pragma unroll
                for (int k = 0; k < 7; ++k) ya[wj][ci][k] = 0.f;

        #pragma unroll 2
        for (int n = 0; n < NNZ; ++n){
            const int hi = psi_hi[ho*NNZ + n];
            const int wi = psi_wi[ho*NNZ + n];
            float ps[7];
            #pragma unroll
            for (int k = 0; k < 7; ++k) ps[k] = psi_v[(k*HOUT + ho)*NNZ + n];
            const int rowb = hi * WIN;
            #pragma unroll
            for (int wj = 0; wj < 3; ++wj){
                int wv = wi + 2*(wo0 + wol + 32*wj);
                wv = (wv >= 720) ? (wv - 720) : (wv >= 360 ? (wv - 360) : wv);
                const int off = rowb + wv;
                float g0 = bp0[off], g1 = bp1[off], g2 = bp2[off], g3 = bp3[off];
                #pragma unroll
                for (int k = 0; k < 7; ++k){
                    float pv = ps[k];
                    ya[wj][0][k] += pv*g0; ya[wj][1][k] += pv*g1;
                    ya[wj][2][k] += pv*g2; ya[wj][3][k] += pv*g3;
                }
            }
        }
        #pragma unroll
        for (int wj = 0; wj < 3; ++wj){
            char* rowp = (char*)yT + (wol + 32*wj)*512;
            #pragma unroll
            for (int k = 0; k < 7; ++k){
                unsigned base = ((unsigned)(k*64 + cq*8)) ^ sw;
                *(unsigned*)(rowp + base)     = pkbf(ya[wj][0][k], ya[wj][1][k]);
                *(unsigned*)(rowp + base + 4) = pkbf(ya[wj][2][k], ya[wj][3][k]);
            }
        }
        __syncthreads();

        const unsigned short* wrow = wbf + (size_t)(co0 + wm*64 + (l & 15))*896
                                         + cc*32 + ((l >> 4) << 3);
        #pragma unroll
        for (int k = 0; k < 7; ++k){
            bf16x8 af[4];
            #pragma unroll
            for (int m = 0; m < 4; ++m)
                af[m] = __builtin_bit_cast(bf16x8,
                          *(const uint4*)(wrow + (size_t)m*16*896 + k*128));
            bf16x8 bfv[3];
            #pragma unroll
            for (int nf = 0; nf < 3; ++nf){
                const int wo_l = wn*48 + nf*16 + (l & 15);
                unsigned off = (unsigned)(wo_l*512)
                             + (((unsigned)(k*64) + ((unsigned)(l >> 4) << 4))
                                ^ ((unsigned)(wo_l & 7) << 4));
                bfv[nf] = __builtin_bit_cast(bf16x8, *(const uint4*)((const char*)yT + off));
            }
            #pragma unroll
            for (int m = 0; m < 4; ++m)
                #pragma unroll
                for (int nf = 0; nf < 3; ++nf)
                    acc[m][nf] = __builtin_amdgcn_mfma_f32_16x16x32_bf16(af[m], bfv[nf], acc[m][nf], 0, 0, 0);
        }
    }

    float s[2] = {0.f, 0.f}, ss[2] = {0.f, 0.f};
    #pragma unroll
    for (int m = 0; m < 4; ++m){
        const int pair = m >> 1;
        const int cob = co0 + wm*64 + m*16 + ((l >> 4) << 2);
        float4 bv = *(const float4*)(bias + cob);
        #pragma unroll
        for (int nf = 0; nf < 3; ++nf){
            const int wo_t = wn*48 + nf*16 + (l & 15);
            if (wo_t < 90){
                #pragma unroll
                for (int r = 0; r < 4; ++r){
                    float v = acc[m][nf][r] + ((const float*)&bv)[r];
                    xdown[((size_t)(b*256 + cob + r)*HOUT + ho)*WOUT + wo0 + wo_t] = v;
                    s[pair] += v; ss[pair] += v*v;
                }
            }
        }
    }
    #pragma unroll
    for (int off = 32; off; off >>= 1){
        s[0] += __shfl_down(s[0], off); ss[0] += __shfl_down(ss[0], off);
        s[1] += __shfl_down(s[1], off); ss[1] += __shfl_down(ss[1], off);
    }
    if (l == 0){
        const int tid = (z*91 + ho)*2 + woh;
        part[(tid*8 + w*2 + 0)*2]     = s[0];
        part[(tid*8 + w*2 + 0)*2 + 1] = ss[0];
        part[(tid*8 + w*2 + 1)*2]     = s[1];
        part[(tid*8 + w*2 + 1)*2 + 1] = ss[1];
    }
}

__global__ __launch_bounds__(256) void k_gn2_final_fb(const float* __restrict__ part,
                                                      float* __restrict__ stat){
    const int bg = blockIdx.x, b = bg >> 3, g = bg & 7, t = threadIdx.x;
    const int coh = g >> 2, gl = g & 3, wm = gl >> 1, pair = gl & 1;
    float s = 0.f, ss = 0.f;
    for (int i = t; i < 364; i += 256){
        int ho = i >> 2, r = i & 3, woh = r >> 1, wn = r & 1;
        int tid = (((b*2 + coh)*91 + ho)*2 + woh);
        int slot = (wm*2 + wn)*2 + pair;
        s  += part[(tid*8 + slot)*2];
        ss += part[(tid*8 + slot)*2 + 1];
    }
    #pragma unroll
    for (int off = 32; off; off >>= 1){ s += __shfl_down(s, off); ss += __shfl_down(ss, off); }
    __shared__ float ls[4][2];
    if ((t & 63) == 0){ ls[t>>6][0] = s; ls[t>>6][1] = ss; }
    __syncthreads();
    if (t == 0){
        s  = ls[0][0] + ls[1][0] + ls[2][0] + ls[3][0];
        ss = ls[0][1] + ls[1][1] + ls[2][1] + ls[3][1];
        float m = s / (float)N_GN2;
        float v = ss / (float)N_GN2 - m*m;
        stat[bg*2]     = m;
        stat[bg*2 + 1] = 1.0f / sqrtf(v + 1e-5f);
    }
}

__global__ __launch_bounds__(256) void k_gn2_apply(float* __restrict__ xd,
                                                   const float* __restrict__ stat,
                                                   const float* __restrict__ g2a,
                                                   const float* __restrict__ be2){
    const int gid = blockIdx.x*256 + threadIdx.x;
    const int stride = gridDim.x*256;
    for (int v = gid; v < 2096640; v += stride){
        float4 q = ((float4*)xd)[v];
        int i  = v << 2;
        int bc = i / 16380;
        int co = bc & 255, b = bc >> 8;
        float m  = stat[(b*8 + (co >> 5))*2];
        float r  = stat[(b*8 + (co >> 5))*2 + 1];
        float a  = r * g2a[co];
        float bb = be2[co] - m*a;
        q.x = gelu_f(__builtin_fmaf(q.x, a, bb));
        q.y = gelu_f(__builtin_fmaf(q.y, a, bb));
        q.z = gelu_f(__builtin_fmaf(q.z, a, bb));
        q.w = gelu_f(__builtin_fmaf(q.w, a, bb));
        ((float4*)xd)[v] = q;
    }
}

extern "C" void kernel_launch(void* const* d_in, const int* in_sizes, int n_in,
                              void* d_out, int out_size, void* d_ws, size_t ws_size,
                              hipStream_t stream){
    const float* x      = (const float*)d_in[0];
    const float* psi_v  = (const float*)d_in[1];
    const int*   psi_hi = (const int*)d_in[2];
    const int*   psi_wi = (const int*)d_in[3];
    const float* weight = (const float*)d_in[4];
    const float* bias   = (const float*)d_in[5];
    const float* g1     = (const float*)d_in[6];
    const float* be1    = (const float*)d_in[7];
    const float* w1     = (const float*)d_in[8];
    const float* b1     = (const float*)d_in[9];
    const float* w2     = (const float*)d_in[10];
    const float* b2     = (const float*)d_in[11];
    const float* g2     = (const float*)d_in[12];
    const float* be2    = (const float*)d_in[13];

    float* skip  = (float*)d_out;
    float* xdown = skip + 16680960;          // 2*128*181*360

    float* ws       = (float*)d_ws;
    float* gn1_part = ws;                                   // 4096 f
    float* gn2_part = ws + 4128;                            // 11648 f (8192 used)
    float* gn2_stat = ws + 15776;                           // 32 f (fallback only)
    unsigned short* wbf = (unsigned short*)(ws + 15808);    // 229376 us -> 130496
    unsigned short* w1f = (unsigned short*)(ws + 130496);   // 65536 us  -> 163264
    float*          b1f = ws + 163264;                      // 512 f     -> 163776
    unsigned short* w2b = (unsigned short*)(ws + 163776);   // 32768 us  -> 180160
    unsigned short* sbf = (unsigned short*)(ws + 180160);   // 16,680,960 us -> 8,520,640
    unsigned short* xdb = sbf;                              // overlay (sbf dead after dfuse build)
    const size_t need = 8520640ull * 4ull;                  // ~34.1 MB

    const bool split = (ws_size >= need);

    k_prep       <<<2432, 256, 0, stream>>>(x, gn1_part, weight, wbf, w2, w2b);
    k_fold       <<<512, 64, 0, stream>>>(gn1_part, w1, b1, g1, be1, w1f, b1f);
    k_mlp        <<<dim3(1019, 2), 256, 0, stream>>>(x, w1f, b1f, w2b, b2,
                                                     skip, split ? sbf : (unsigned short*)nullptr);
    if (split){
        k_dfuse     <<<dim3(256, 2), 256, 0, stream>>>(sbf, psi_v, psi_hi, psi_wi,
                                                       wbf, bias, xdb, gn2_part);
        k_gn2_apply_s<<<512, 256, 0, stream>>>(xdb, xdown, gn2_part, g2, be2);
    } else {
        k_disco_fb <<<dim3(2, 91, 4), 256, 0, stream>>>(skip, psi_v, psi_hi, psi_wi,
                                                        wbf, bias, xdown, gn2_part);
        k_gn2_final_fb<<<16, 256, 0, stream>>>(gn2_part, gn2_stat);
        k_gn2_apply<<<2048, 256, 0, stream>>>(xdown, gn2_stat, g2, be2);
    }
}